// Round 9
// baseline (2895.616 us; speedup 1.0000x reference)
//
#include <hip/hip_runtime.h>

typedef __attribute__((ext_vector_type(8))) short bf16x8;
typedef __attribute__((ext_vector_type(4))) float f32x4;
typedef __attribute__((ext_vector_type(4))) unsigned int u32x4;
typedef __attribute__((ext_vector_type(4))) unsigned short u16x4;

#define NE 8
#define NT 2048   // tokens per expert (B*C)
#define NM 2048
#define NH 7168

// Raw barrier (no implicit vmcnt(0) drain) + counted vmcnt waits.
#define BAR() asm volatile("s_barrier" ::: "memory")
#define WAITV(N) asm volatile("s_waitcnt vmcnt(" #N ")" ::: "memory")

__device__ __forceinline__ unsigned short f2bf(float f) {
    unsigned int u = __float_as_uint(f);
    return (unsigned short)((u + 0x7fffu + ((u >> 16) & 1u)) >> 16);  // RNE
}

__device__ __forceinline__ void gld16(const void* g, void* l) {
    __builtin_amdgcn_global_load_lds(
        (const __attribute__((address_space(1))) void*)g,
        (__attribute__((address_space(3))) void*)l, 16, 0, 0);
}

// ============================ conversion kernels ============================

__global__ __launch_bounds__(256) void convert_x_kernel(
        const float* __restrict__ in, unsigned short* __restrict__ out) {
    const int i = blockIdx.x * 256 + threadIdx.x;      // f32x4 index
    f32x4 a = ((const f32x4*)in)[i];
    ((u16x4*)out)[i] = (u16x4){f2bf(a[0]), f2bf(a[1]), f2bf(a[2]), f2bf(a[3])};
}

// w [E][R][C] fp32 -> wT [E][C][R] bf16 (plain transpose), 64x64 LDS tiles.
__global__ __launch_bounds__(256) void convert_wT_kernel(
        const float* __restrict__ in, unsigned short* __restrict__ out,
        int R, int C) {
    const int t = threadIdx.x;
    const int e = blockIdx.y;
    const int tiles_c = C >> 6;
    const int tr = blockIdx.x / tiles_c, tc = blockIdx.x % tiles_c;

    const float* ip = in + (size_t)e * R * C + (size_t)(tr * 64) * C + tc * 64;
    unsigned short* op = out + (size_t)e * R * C + (size_t)(tc * 64) * R + tr * 64;

    __shared__ unsigned short tl[64][68];

    const int rr = t >> 4, c4 = (t & 15) * 4;
#pragma unroll
    for (int q = 0; q < 4; ++q) {
        const int r = q * 16 + rr;
        f32x4 v = *(const f32x4*)(ip + (size_t)r * C + c4);
        *(u16x4*)&tl[r][c4] = (u16x4){f2bf(v[0]), f2bf(v[1]), f2bf(v[2]), f2bf(v[3])};
    }
    __syncthreads();
#pragma unroll
    for (int q = 0; q < 4; ++q) {
        const int oc = q * 16 + rr;          // output row = input col
        u16x4 v = (u16x4){tl[c4][oc], tl[c4 + 1][oc], tl[c4 + 2][oc], tl[c4 + 3][oc]};
        *(u16x4*)(op + (size_t)oc * R + c4) = v;
    }
}

// w1,w3 [E][M][H] fp32 -> wcat [E][2H][M] bf16, transposed + 16-row interleaved:
// wcat row = 32*(h>>4) + 16*which + (h&15), which: 0=w1(gate), 1=w3(up).
__global__ __launch_bounds__(256) void convert_w13_kernel(
        const float* __restrict__ w1, const float* __restrict__ w3,
        unsigned short* __restrict__ wcat) {
    const int t = threadIdx.x;
    const int e = blockIdx.y;
    const int tiles_c = NH >> 6;              // 112
    const int tr = blockIdx.x / tiles_c, tc = blockIdx.x % tiles_c;

    __shared__ unsigned short tl[64][68];
    const int rr = t >> 4, c4 = (t & 15) * 4;
    unsigned short* ob = wcat + (size_t)e * (2 * NH) * NM + (size_t)(tc * 128) * NM + tr * 64;

#pragma unroll
    for (int pass = 0; pass < 2; ++pass) {
        const float* ip = (pass ? w3 : w1) + (size_t)e * NM * NH + (size_t)(tr * 64) * NH + tc * 64;
        if (pass) __syncthreads();            // tl reuse
#pragma unroll
        for (int q = 0; q < 4; ++q) {
            const int r = q * 16 + rr;
            f32x4 v = *(const f32x4*)(ip + (size_t)r * NH + c4);
            *(u16x4*)&tl[r][c4] = (u16x4){f2bf(v[0]), f2bf(v[1]), f2bf(v[2]), f2bf(v[3])};
        }
        __syncthreads();
#pragma unroll
        for (int q = 0; q < 4; ++q) {
            const int oc = q * 16 + rr;       // h within tile
            const int orow = ((oc >> 4) * 32) + pass * 16 + (oc & 15);
            u16x4 v = (u16x4){tl[c4][oc], tl[c4 + 1][oc], tl[c4 + 2][oc], tl[c4 + 3][oc]};
            *(u16x4*)(ob + (size_t)orow * NM + c4) = v;
        }
    }
}

// =============== GEMM1 (256^2, B-direct): hid = silu(gate)*up ===============
// A = xb [E*T][M] staged to LDS (frag-major, 0-conflict); B = wcat [E][2H][M]
// loaded DIRECTLY global->VGPR per-lane 16B (identical bytes to the LDS path,
// r8-verified mapping). Cuts LDS reads/iter from 96KB to 64KB (was the 40%-
// MfmaUtil cap). vmcnt ledger (per-iter issues: bload:4 then stageA:2):
//   steady queue after issues = 14; WAITV(12) => A(t) in LDS (pre-BAR publish);
//   WAITV(8) => bload(t) in regs, A(t+1)/bload(t+1)/A(t+2) still flying.
// Tails: 10/6 then 4/0. bfA/bfB ping-pong via 2x-unrolled loop (no dyn index).
__global__ __launch_bounds__(512, 2) void gemm1p_kernel(
        const unsigned short* __restrict__ xb, const unsigned short* __restrict__ wcat,
        unsigned short* __restrict__ hid) {
    const int tid = threadIdx.x;
    const int lane = tid & 63, wv = tid >> 6;          // 8 waves
    const int wr = wv >> 2, wc = wv & 3;               // 2M x 4N
    const int e = blockIdx.y;
    const int d = blockIdx.x;                          // 0..447
    const int l = (d & 7) * 56 + (d >> 3);             // XCD-contiguous (448%8==0)
    const int ct = l >> 3, tt = l & 7;                 // ctile 0..55, ttile 0..7

    const unsigned short* ag = xb   + (size_t)(e * NT + tt * 256) * NM;
    const unsigned short* bg = wcat + (size_t)e * (2 * NH) * NM + (size_t)(ct * 256) * NM;
    unsigned short* hg = hid + (size_t)(e * NT + tt * 256) * NH + ct * 128;

    // 3 buf x A(16 frags x 512 shorts) = 48 KiB
    __shared__ __align__(16) unsigned short lds[3 * 8192];

    const int frow = lane & 15;            // staging src row within frag
    const int fks  = (lane >> 4) * 8;      // k offset within 32
    const int la   = lane * 8;             // frag-major read: lane*16B
    const int lr   = lane & 15, lq = lane >> 4;

    f32x4 acc[8][4];
#pragma unroll
    for (int m = 0; m < 8; ++m)
#pragma unroll
        for (int n = 0; n < 4; ++n) acc[m][n] = (f32x4){0.f, 0.f, 0.f, 0.f};

    auto stageA = [&](int t, int buf) {
        unsigned short* dst = lds + buf * 8192 + wv * 512;
        const unsigned short* src = ag + (size_t)(wv * 16 + frow) * NM + t * 32 + fks;
        gld16(src, dst);
        gld16(src + (size_t)128 * NM, dst + 8 * 512);
    };
    // per-lane direct B-frag loads: lane l <- B[row wc*64+n*16+(l&15)][k-run (l>>4)*8]
    auto bload = [&](bf16x8 (&bf)[4], int t) {
#pragma unroll
        for (int n = 0; n < 4; ++n)
            bf[n] = *(const bf16x8*)(bg + (size_t)(wc * 64 + n * 16 + lr) * NM + t * 32 + fks);
    };

    auto body = [&](int buf, const bf16x8 (&bf)[4]) {
        const unsigned short* bA = lds + buf * 8192;
        bf16x8 af[4];
#pragma unroll
        for (int m = 0; m < 4; ++m)
            af[m] = *(const bf16x8*)(bA + (wr * 8 + m) * 512 + la);
        __builtin_amdgcn_s_setprio(1);
#pragma unroll
        for (int m = 0; m < 4; ++m)
#pragma unroll
            for (int n = 0; n < 4; ++n)
                acc[m][n] = __builtin_amdgcn_mfma_f32_16x16x32_bf16(af[m], bf[n], acc[m][n], 0, 0, 0);
        __builtin_amdgcn_s_setprio(0);
#pragma unroll
        for (int m = 0; m < 4; ++m)
            af[m] = *(const bf16x8*)(bA + (wr * 8 + 4 + m) * 512 + la);
        __builtin_amdgcn_s_setprio(1);
#pragma unroll
        for (int m = 0; m < 4; ++m)
#pragma unroll
            for (int n = 0; n < 4; ++n)
                acc[4 + m][n] = __builtin_amdgcn_mfma_f32_16x16x32_bf16(af[m], bf[n], acc[4 + m][n], 0, 0, 0);
        __builtin_amdgcn_s_setprio(0);
    };

    const int NKT = NM / 32;               // 64; NKT-2 = 62 (even)
    bf16x8 bfA[4], bfB[4];

    // prologue establishes queue = [A(0):2, bload(0):4, A(1):2]
    stageA(0, 0);
    bload(bfA, 0);
    stageA(1, 1);

    int buf = 0, nbuf = 2;
    for (int t = 0; t < NKT - 2; t += 2) {
        bload(bfB, t + 1);
        stageA(t + 2, nbuf);
        WAITV(12); BAR(); WAITV(8);
        body(buf, bfA);
        BAR();
        buf = (buf == 2) ? 0 : buf + 1;
        nbuf = (nbuf == 2) ? 0 : nbuf + 1;

        bload(bfA, t + 2);
        stageA(t + 3, nbuf);
        WAITV(12); BAR(); WAITV(8);
        body(buf, bfB);
        BAR();
        buf = (buf == 2) ? 0 : buf + 1;
        nbuf = (nbuf == 2) ? 0 : nbuf + 1;
    }
    // tail t = NKT-2 (regs bfA): queue = A(NKT-2):2, bload(NKT-2):4, A(NKT-1):2
    bload(bfB, NKT - 1);
    WAITV(10); BAR(); WAITV(6);
    body(buf, bfA);
    BAR();
    buf = (buf == 2) ? 0 : buf + 1;
    // tail t = NKT-1 (regs bfB): queue = A(NKT-1):2, bload(NKT-1):4
    WAITV(4); BAR(); WAITV(0);
    body(buf, bfB);

    // epilogue: N-frags alternate gate(even)/up(odd) with identical lane map
#pragma unroll
    for (int mf = 0; mf < 8; ++mf)
#pragma unroll
        for (int p = 0; p < 2; ++p)
#pragma unroll
            for (int i = 0; i < 4; ++i) {
                const float g = acc[mf][2 * p][i];
                const float u = acc[mf][2 * p + 1][i];
                const float s = g / (1.f + __expf(-g));
                const int r = wr * 128 + mf * 16 + lq * 4 + i;
                const int h = wc * 32 + p * 16 + lr;
                hg[(size_t)r * NH + h] = f2bf(s * u);
            }
}

// ============ GEMM2 (256^2, B-direct): out = hid * w2T^T, fp32 out ============
__global__ __launch_bounds__(512, 2) void gemm2p_kernel(
        const unsigned short* __restrict__ hid, const unsigned short* __restrict__ w2t,
        float* __restrict__ out) {
    const int tid = threadIdx.x;
    const int lane = tid & 63, wv = tid >> 6;
    const int wr = wv >> 2, wc = wv & 3;
    const int e = blockIdx.y;
    const int d = blockIdx.x;                          // 0..63
    const int l = (d & 7) * 8 + (d >> 3);
    const int mt = l >> 3, tt = l & 7;                 // mtile 0..7, ttile 0..7

    const unsigned short* ag = hid + (size_t)(e * NT + tt * 256) * NH;
    const unsigned short* bg = w2t + (size_t)e * NM * NH + (size_t)(mt * 256) * NH;
    float* og = out + (size_t)(e * NT + tt * 256) * NM + mt * 256;

    __shared__ __align__(16) unsigned short lds[3 * 8192];

    const int frow = lane & 15;
    const int fks  = (lane >> 4) * 8;
    const int la   = lane * 8;
    const int lr   = lane & 15, lq = lane >> 4;

    f32x4 acc[8][4];
#pragma unroll
    for (int m = 0; m < 8; ++m)
#pragma unroll
        for (int n = 0; n < 4; ++n) acc[m][n] = (f32x4){0.f, 0.f, 0.f, 0.f};

    auto stageA = [&](int t, int buf) {
        unsigned short* dst = lds + buf * 8192 + wv * 512;
        const unsigned short* src = ag + (size_t)(wv * 16 + frow) * NH + t * 32 + fks;
        gld16(src, dst);
        gld16(src + (size_t)128 * NH, dst + 8 * 512);
    };
    auto bload = [&](bf16x8 (&bf)[4], int t) {
#pragma unroll
        for (int n = 0; n < 4; ++n)
            bf[n] = *(const bf16x8*)(bg + (size_t)(wc * 64 + n * 16 + lr) * NH + t * 32 + fks);
    };

    auto body = [&](int buf, const bf16x8 (&bf)[4]) {
        const unsigned short* bA = lds + buf * 8192;
        bf16x8 af[4];
#pragma unroll
        for (int m = 0; m < 4; ++m)
            af[m] = *(const bf16x8*)(bA + (wr * 8 + m) * 512 + la);
        __builtin_amdgcn_s_setprio(1);
#pragma unroll
        for (int m = 0; m < 4; ++m)
#pragma unroll
            for (int n = 0; n < 4; ++n)
                acc[m][n] = __builtin_amdgcn_mfma_f32_16x16x32_bf16(af[m], bf[n], acc[m][n], 0, 0, 0);
        __builtin_amdgcn_s_setprio(0);
#pragma unroll
        for (int m = 0; m < 4; ++m)
            af[m] = *(const bf16x8*)(bA + (wr * 8 + 4 + m) * 512 + la);
        __builtin_amdgcn_s_setprio(1);
#pragma unroll
        for (int m = 0; m < 4; ++m)
#pragma unroll
            for (int n = 0; n < 4; ++n)
                acc[4 + m][n] = __builtin_amdgcn_mfma_f32_16x16x32_bf16(af[m], bf[n], acc[4 + m][n], 0, 0, 0);
        __builtin_amdgcn_s_setprio(0);
    };

    const int NKT = NH / 32;               // 224; NKT-2 = 222 (even)
    bf16x8 bfA[4], bfB[4];

    stageA(0, 0);
    bload(bfA, 0);
    stageA(1, 1);

    int buf = 0, nbuf = 2;
    for (int t = 0; t < NKT - 2; t += 2) {
        bload(bfB, t + 1);
        stageA(t + 2, nbuf);
        WAITV(12); BAR(); WAITV(8);
        body(buf, bfA);
        BAR();
        buf = (buf == 2) ? 0 : buf + 1;
        nbuf = (nbuf == 2) ? 0 : nbuf + 1;

        bload(bfA, t + 2);
        stageA(t + 3, nbuf);
        WAITV(12); BAR(); WAITV(8);
        body(buf, bfB);
        BAR();
        buf = (buf == 2) ? 0 : buf + 1;
        nbuf = (nbuf == 2) ? 0 : nbuf + 1;
    }
    bload(bfB, NKT - 1);
    WAITV(10); BAR(); WAITV(6);
    body(buf, bfA);
    BAR();
    buf = (buf == 2) ? 0 : buf + 1;
    WAITV(4); BAR(); WAITV(0);
    body(buf, bfB);

#pragma unroll
    for (int mf = 0; mf < 8; ++mf)
#pragma unroll
        for (int n = 0; n < 4; ++n)
#pragma unroll
            for (int i = 0; i < 4; ++i) {
                const int r = wr * 128 + mf * 16 + lq * 4 + i;
                const int c = wc * 64 + n * 16 + lr;
                og[(size_t)r * NM + c] = acc[mf][n][i];
            }
}

// ===================== fallback (round-1, fused-convert) =====================
#define ROWB 80
#define TILEB (128 * ROWB)

__global__ __launch_bounds__(256, 2) void gemm1_fb_kernel(
        const float* __restrict__ x, const float* __restrict__ w1,
        const float* __restrict__ w3, unsigned short* __restrict__ hid) {
    const int tid = threadIdx.x;
    const int e = blockIdx.y;
    const int d = blockIdx.x;
    const int l = (d & 7) * 112 + (d >> 3);
    const int hn = l >> 4, tm = l & 15;

    const float* xg  = x  + (size_t)(e * NT + tm * 128) * NM;
    const float* w1g = w1 + (size_t)e * NM * NH + hn * 128;
    const float* w3g = w3 + (size_t)e * NM * NH + hn * 128;
    unsigned short* hg = hid + (size_t)(e * NT + tm * 128) * NH + hn * 128;

    __shared__ __align__(16) unsigned char lds[2 * 3 * TILEB];

    const int a_r = tid >> 3, a_c4 = tid & 7;
    const int w_kq = (tid >> 2) & 7;
    const int w_cg = ((tid >> 5) << 2) | (tid & 3);

    const int lane = tid & 63;
    const int wv = tid >> 6;
    const int r0w = (wv >> 1) * 64, c0w = (wv & 1) * 64;
    const int lr = lane & 15, lq = lane >> 4;

    f32x4 accg[4][4], accu[4][4];
#pragma unroll
    for (int m = 0; m < 4; ++m)
#pragma unroll
        for (int n = 0; n < 4; ++n) {
            accg[m][n] = (f32x4){0.f, 0.f, 0.f, 0.f};
            accu[m][n] = (f32x4){0.f, 0.f, 0.f, 0.f};
        }

    f32x4 la0, la1, la2, la3;
    f32x4 l10, l11, l12, l13, l30, l31, l32, l33;

    auto stage_load = [&](int ks) {
        const int k0 = ks * 32;
        const float* pa = xg + (size_t)a_r * NM + k0 + a_c4 * 4;
        la0 = *(const f32x4*)(pa);
        la1 = *(const f32x4*)(pa + 32 * NM);
        la2 = *(const f32x4*)(pa + 64 * NM);
        la3 = *(const f32x4*)(pa + 96 * NM);
        const float* p1 = w1g + (size_t)(k0 + w_kq * 4) * NH + w_cg * 4;
        l10 = *(const f32x4*)(p1);
        l11 = *(const f32x4*)(p1 + NH);
        l12 = *(const f32x4*)(p1 + 2 * NH);
        l13 = *(const f32x4*)(p1 + 3 * NH);
        const float* p3 = w3g + (size_t)(k0 + w_kq * 4) * NH + w_cg * 4;
        l30 = *(const f32x4*)(p3);
        l31 = *(const f32x4*)(p3 + NH);
        l32 = *(const f32x4*)(p3 + 2 * NH);
        l33 = *(const f32x4*)(p3 + 3 * NH);
    };

    auto stage_write = [&](int buf) {
        unsigned char* base = lds + buf * (3 * TILEB);
        unsigned char* pa = base + a_r * ROWB + a_c4 * 8;
        *(u16x4*)(pa)             = (u16x4){f2bf(la0[0]), f2bf(la0[1]), f2bf(la0[2]), f2bf(la0[3])};
        *(u16x4*)(pa + 32 * ROWB) = (u16x4){f2bf(la1[0]), f2bf(la1[1]), f2bf(la1[2]), f2bf(la1[3])};
        *(u16x4*)(pa + 64 * ROWB) = (u16x4){f2bf(la2[0]), f2bf(la2[1]), f2bf(la2[2]), f2bf(la2[3])};
        *(u16x4*)(pa + 96 * ROWB) = (u16x4){f2bf(la3[0]), f2bf(la3[1]), f2bf(la3[2]), f2bf(la3[3])};
        unsigned char* pw1 = base + TILEB + w_kq * 8;
#pragma unroll
        for (int j = 0; j < 4; ++j) {
            const int c = w_cg * 4 + j;
            *(u16x4*)(pw1 + c * ROWB) =
                (u16x4){f2bf(l10[j]), f2bf(l11[j]), f2bf(l12[j]), f2bf(l13[j])};
        }
        unsigned char* pw3 = base + 2 * TILEB + w_kq * 8;
#pragma unroll
        for (int j = 0; j < 4; ++j) {
            const int c = w_cg * 4 + j;
            *(u16x4*)(pw3 + c * ROWB) =
                (u16x4){f2bf(l30[j]), f2bf(l31[j]), f2bf(l32[j]), f2bf(l33[j])};
        }
    };

    auto compute = [&](int buf) {
        const unsigned char* base = lds + buf * (3 * TILEB);
        bf16x8 af[4], b1f[4], b3f[4];
#pragma unroll
        for (int m = 0; m < 4; ++m)
            af[m] = *(const bf16x8*)(base + (r0w + m * 16 + lr) * ROWB + lq * 16);
#pragma unroll
        for (int n = 0; n < 4; ++n) {
            b1f[n] = *(const bf16x8*)(base + TILEB + (c0w + n * 16 + lr) * ROWB + lq * 16);
            b3f[n] = *(const bf16x8*)(base + 2 * TILEB + (c0w + n * 16 + lr) * ROWB + lq * 16);
        }
#pragma unroll
        for (int m = 0; m < 4; ++m)
#pragma unroll
            for (int n = 0; n < 4; ++n) {
                accg[m][n] = __builtin_amdgcn_mfma_f32_16x16x32_bf16(af[m], b1f[n], accg[m][n], 0, 0, 0);
                accu[m][n] = __builtin_amdgcn_mfma_f32_16x16x32_bf16(af[m], b3f[n], accu[m][n], 0, 0, 0);
            }
    };

    stage_load(0);
    stage_write(0);
    __syncthreads();
    int cur = 0;
    const int NK = NM / 32;
    for (int ks = 0; ks < NK; ++ks) {
        const bool more = (ks + 1 < NK);
        if (more) stage_load(ks + 1);
        compute(cur);
        if (more) {
            stage_write(cur ^ 1);
            __syncthreads();
        }
        cur ^= 1;
    }

#pragma unroll
    for (int m = 0; m < 4; ++m)
#pragma unroll
        for (int n = 0; n < 4; ++n)
#pragma unroll
            for (int i = 0; i < 4; ++i) {
                const float g = accg[m][n][i];
                const float u = accu[m][n][i];
                const float s = g / (1.f + __expf(-g));
                const int r = r0w + m * 16 + lq * 4 + i;
                const int c = c0w + n * 16 + lr;
                hg[(size_t)r * NH + c] = f2bf(s * u);
            }
}

__global__ __launch_bounds__(256, 2) void gemm2_fb_kernel(
        const unsigned short* __restrict__ hid, const float* __restrict__ w2,
        float* __restrict__ out) {
    const int tid = threadIdx.x;
    const int e = blockIdx.y;
    const int d = blockIdx.x;
    const int l = (d & 7) * 32 + (d >> 3);
    const int mn = l >> 4, tm = l & 15;

    const unsigned short* ag = hid + (size_t)(e * NT + tm * 128) * NH;
    const float* wg = w2 + (size_t)e * NH * NM + mn * 128;
    float* og = out + (size_t)(e * NT + tm * 128) * NM + mn * 128;

    __shared__ __align__(16) unsigned char lds[2 * 2 * TILEB];

    const int a_row = tid >> 2, a_ch = tid & 3;
    const int w_kq = (tid >> 2) & 7;
    const int w_cg = ((tid >> 5) << 2) | (tid & 3);

    const int lane = tid & 63;
    const int wv = tid >> 6;
    const int r0w = (wv >> 1) * 64, c0w = (wv & 1) * 64;
    const int lr = lane & 15, lq = lane >> 4;

    f32x4 acc[4][4];
#pragma unroll
    for (int m = 0; m < 4; ++m)
#pragma unroll
        for (int n = 0; n < 4; ++n) acc[m][n] = (f32x4){0.f, 0.f, 0.f, 0.f};

    u32x4 lau0, lau1;
    f32x4 lw0, lw1, lw2, lw3;

    auto stage_load = [&](int ks) {
        const int k0 = ks * 32;
        lau0 = *(const u32x4*)(ag + (size_t)a_row * NH + k0 + a_ch * 8);
        lau1 = *(const u32x4*)(ag + (size_t)(a_row + 64) * NH + k0 + a_ch * 8);
        const float* p = wg + (size_t)(k0 + w_kq * 4) * NM + w_cg * 4;
        lw0 = *(const f32x4*)(p);
        lw1 = *(const f32x4*)(p + NM);
        lw2 = *(const f32x4*)(p + 2 * NM);
        lw3 = *(const f32x4*)(p + 3 * NM);
    };

    auto stage_write = [&](int buf) {
        unsigned char* base = lds + buf * (2 * TILEB);
        *(u32x4*)(base + a_row * ROWB + a_ch * 16) = lau0;
        *(u32x4*)(base + (a_row + 64) * ROWB + a_ch * 16) = lau1;
        unsigned char* pw = base + TILEB + w_kq * 8;
#pragma unroll
        for (int j = 0; j < 4; ++j) {
            const int c = w_cg * 4 + j;
            *(u16x4*)(pw + c * ROWB) =
                (u16x4){f2bf(lw0[j]), f2bf(lw1[j]), f2bf(lw2[j]), f2bf(lw3[j])};
        }
    };

    auto compute = [&](int buf) {
        const unsigned char* base = lds + buf * (2 * TILEB);
        bf16x8 af[4], bf[4];
#pragma unroll
        for (int m = 0; m < 4; ++m)
            af[m] = *(const bf16x8*)(base + (r0w + m * 16 + lr) * ROWB + lq * 16);
#pragma unroll
        for (int n = 0; n < 4; ++n)
            bf[n] = *(const bf16x8*)(base + TILEB + (c0w + n * 16 + lr) * ROWB + lq * 16);
#pragma unroll
        for (int m = 0; m < 4; ++m)
#pragma unroll
            for (int n = 0; n < 4; ++n)
                acc[m][n] = __builtin_amdgcn_mfma_f32_16x16x32_bf16(af[m], bf[n], acc[m][n], 0, 0, 0);
    };

    stage_load(0);
    stage_write(0);
    __syncthreads();
    int cur = 0;
    const int NK = NH / 32;
    for (int ks = 0; ks < NK; ++ks) {
        const bool more = (ks + 1 < NK);
        if (more) stage_load(ks + 1);
        compute(cur);
        if (more) {
            stage_write(cur ^ 1);
            __syncthreads();
        }
        cur ^= 1;
    }

#pragma unroll
    for (int m = 0; m < 4; ++m)
#pragma unroll
        for (int n = 0; n < 4; ++n)
#pragma unroll
            for (int i = 0; i < 4; ++i) {
                const int r = r0w + m * 16 + lq * 4 + i;
                const int c = c0w + n * 16 + lr;
                og[(size_t)r * NM + c] = acc[m][n][i];
            }
}

// ================================ launcher ================================

extern "C" void kernel_launch(void* const* d_in, const int* in_sizes, int n_in,
                              void* d_out, int out_size, void* d_ws, size_t ws_size,
                              hipStream_t stream) {
    const float* x  = (const float*)d_in[0];
    const float* w1 = (const float*)d_in[1];
    const float* w2 = (const float*)d_in[2];
    const float* w3 = (const float*)d_in[3];
    float* out = (float*)d_out;

    const size_t XB_SZ   = (size_t)NE * NT * NM * 2;        //  64 MiB
    const size_t WCAT_SZ = (size_t)NE * 2 * NH * NM * 2;    // 448 MiB
    const size_t HID_SZ  = (size_t)NE * NT * NH * 2;        // 224 MiB
    const size_t NEED = XB_SZ + WCAT_SZ + HID_SZ;           // 736 MiB

    if (ws_size >= NEED) {
        unsigned char* ws = (unsigned char*)d_ws;
        unsigned short* xbp  = (unsigned short*)(ws);
        unsigned short* wcat = (unsigned short*)(ws + XB_SZ);
        unsigned short* hidb = (unsigned short*)(ws + XB_SZ + WCAT_SZ);
        unsigned short* w2t  = (unsigned short*)(ws);   // reuses xb/wcat after gemm1

        convert_x_kernel<<<dim3((NE * NT * NM) / 1024), 256, 0, stream>>>(x, xbp);
        convert_w13_kernel<<<dim3((NM / 64) * (NH / 64), NE), 256, 0, stream>>>(w1, w3, wcat);
        gemm1p_kernel<<<dim3(448, NE), 512, 0, stream>>>(xbp, wcat, hidb);
        convert_wT_kernel<<<dim3((NH / 64) * (NM / 64), NE), 256, 0, stream>>>(w2, w2t, NH, NM);
        gemm2p_kernel<<<dim3(64, NE), 512, 0, stream>>>(hidb, w2t, out);
    } else {
        unsigned short* hid = (unsigned short*)d_ws;
        gemm1_fb_kernel<<<dim3(896, NE), 256, 0, stream>>>(x, w1, w3, hid);
        gemm2_fb_kernel<<<dim3(256, NE), 256, 0, stream>>>(hid, w2, out);
    }
}

// Round 10
// 2009.272 us; speedup vs baseline: 1.4411x; 1.4411x over previous
//
#include <hip/hip_runtime.h>

typedef __attribute__((ext_vector_type(8))) short bf16x8;
typedef __attribute__((ext_vector_type(4))) float f32x4;
typedef __attribute__((ext_vector_type(4))) unsigned int u32x4;
typedef __attribute__((ext_vector_type(4))) unsigned short u16x4;

#define NE 8
#define NT 2048   // tokens per expert (B*C)
#define NM 2048
#define NH 7168

// Raw barrier (no implicit vmcnt(0) drain) + counted vmcnt waits.
#define BAR() asm volatile("s_barrier" ::: "memory")
#define WAITV(N) asm volatile("s_waitcnt vmcnt(" #N ")" ::: "memory")

__device__ __forceinline__ unsigned short f2bf(float f) {
    unsigned int u = __float_as_uint(f);
    return (unsigned short)((u + 0x7fffu + ((u >> 16) & 1u)) >> 16);  // RNE
}

__device__ __forceinline__ void gld16(const void* g, void* l) {
    __builtin_amdgcn_global_load_lds(
        (const __attribute__((address_space(1))) void*)g,
        (__attribute__((address_space(3))) void*)l, 16, 0, 0);
}

// ============================ conversion kernels ============================

__global__ __launch_bounds__(256) void convert_x_kernel(
        const float* __restrict__ in, unsigned short* __restrict__ out) {
    const int i = blockIdx.x * 256 + threadIdx.x;      // f32x4 index
    f32x4 a = ((const f32x4*)in)[i];
    ((u16x4*)out)[i] = (u16x4){f2bf(a[0]), f2bf(a[1]), f2bf(a[2]), f2bf(a[3])};
}

// w [E][R][C] fp32 -> wT [E][C][R] bf16 (plain transpose), 64x64 LDS tiles.
__global__ __launch_bounds__(256) void convert_wT_kernel(
        const float* __restrict__ in, unsigned short* __restrict__ out,
        int R, int C) {
    const int t = threadIdx.x;
    const int e = blockIdx.y;
    const int tiles_c = C >> 6;
    const int tr = blockIdx.x / tiles_c, tc = blockIdx.x % tiles_c;

    const float* ip = in + (size_t)e * R * C + (size_t)(tr * 64) * C + tc * 64;
    unsigned short* op = out + (size_t)e * R * C + (size_t)(tc * 64) * R + tr * 64;

    __shared__ unsigned short tl[64][68];

    const int rr = t >> 4, c4 = (t & 15) * 4;
#pragma unroll
    for (int q = 0; q < 4; ++q) {
        const int r = q * 16 + rr;
        f32x4 v = *(const f32x4*)(ip + (size_t)r * C + c4);
        *(u16x4*)&tl[r][c4] = (u16x4){f2bf(v[0]), f2bf(v[1]), f2bf(v[2]), f2bf(v[3])};
    }
    __syncthreads();
#pragma unroll
    for (int q = 0; q < 4; ++q) {
        const int oc = q * 16 + rr;          // output row = input col
        u16x4 v = (u16x4){tl[c4][oc], tl[c4 + 1][oc], tl[c4 + 2][oc], tl[c4 + 3][oc]};
        *(u16x4*)(op + (size_t)oc * R + c4) = v;
    }
}

// w1,w3 [E][M][H] fp32 -> wcat [E][2H][M] bf16, transposed + 16-row interleaved:
// wcat row = 32*(h>>4) + 16*which + (h&15), which: 0=w1(gate), 1=w3(up).
__global__ __launch_bounds__(256) void convert_w13_kernel(
        const float* __restrict__ w1, const float* __restrict__ w3,
        unsigned short* __restrict__ wcat) {
    const int t = threadIdx.x;
    const int e = blockIdx.y;
    const int tiles_c = NH >> 6;              // 112
    const int tr = blockIdx.x / tiles_c, tc = blockIdx.x % tiles_c;

    __shared__ unsigned short tl[64][68];
    const int rr = t >> 4, c4 = (t & 15) * 4;
    unsigned short* ob = wcat + (size_t)e * (2 * NH) * NM + (size_t)(tc * 128) * NM + tr * 64;

#pragma unroll
    for (int pass = 0; pass < 2; ++pass) {
        const float* ip = (pass ? w3 : w1) + (size_t)e * NM * NH + (size_t)(tr * 64) * NH + tc * 64;
        if (pass) __syncthreads();            // tl reuse
#pragma unroll
        for (int q = 0; q < 4; ++q) {
            const int r = q * 16 + rr;
            f32x4 v = *(const f32x4*)(ip + (size_t)r * NH + c4);
            *(u16x4*)&tl[r][c4] = (u16x4){f2bf(v[0]), f2bf(v[1]), f2bf(v[2]), f2bf(v[3])};
        }
        __syncthreads();
#pragma unroll
        for (int q = 0; q < 4; ++q) {
            const int oc = q * 16 + rr;       // h within tile
            const int orow = ((oc >> 4) * 32) + pass * 16 + (oc & 15);
            u16x4 v = (u16x4){tl[c4][oc], tl[c4 + 1][oc], tl[c4 + 2][oc], tl[c4 + 3][oc]};
            *(u16x4*)(ob + (size_t)orow * NM + c4) = v;
        }
    }
}

// =============== GEMM1 (256^2 fine-phase): hid = silu(gate)*up ===============
// R8 structure (best measured: 1081us, MfmaUtil 40%, 0 conflicts) with the LDS
// cut from 3 buffers to 2 (96KB -> 64KB) => 2 blocks/CU (4 waves/SIMD): the
// 40% cap was read/MFMA phase serialization at 2 waves/SIMD; cross-block TLP
// hides it (m114). vmcnt ledger: per iter issues A(t+1):2 + B(t+1):2; queue=8
// at wait; WAITV(4) => tile t fully landed. Publish: WAITV -> BAR -> reads.
// Anti-dep: restage of buf happens after the end-of-iter BAR of the iter that
// read it. Tail: WAITV(0).
__global__ __launch_bounds__(512, 2) void gemm1p_kernel(
        const unsigned short* __restrict__ xb, const unsigned short* __restrict__ wcat,
        unsigned short* __restrict__ hid) {
    const int tid = threadIdx.x;
    const int lane = tid & 63, wv = tid >> 6;          // 8 waves
    const int wr = wv >> 2, wc = wv & 3;               // 2M x 4N
    const int e = blockIdx.y;
    const int d = blockIdx.x;                          // 0..447
    const int l = (d & 7) * 56 + (d >> 3);             // XCD-contiguous (448%8==0)
    const int ct = l >> 3, tt = l & 7;                 // ctile 0..55, ttile 0..7

    const unsigned short* ag = xb   + (size_t)(e * NT + tt * 256) * NM;
    const unsigned short* bg = wcat + (size_t)e * (2 * NH) * NM + (size_t)(ct * 256) * NM;
    unsigned short* hg = hid + (size_t)(e * NT + tt * 256) * NH + ct * 128;

    // 2 buf x (A 16 frags + B 16 frags) x 512 shorts = 64 KiB
    __shared__ __align__(16) unsigned short lds[2 * 16384];

    const int frow = lane & 15;            // staging src row within frag
    const int fks  = (lane >> 4) * 8;      // k offset within 32
    const int la   = lane * 8;             // frag-major read: lane*16B
    const int lr   = lane & 15, lq = lane >> 4;

    f32x4 acc[8][4];
#pragma unroll
    for (int m = 0; m < 8; ++m)
#pragma unroll
        for (int n = 0; n < 4; ++n) acc[m][n] = (f32x4){0.f, 0.f, 0.f, 0.f};

    // wave wv stages frags wv and wv+8 of each 16-frag tile (2 gld16/thread each)
    auto stageA = [&](int t, int buf) {
        unsigned short* dst = lds + buf * 16384 + wv * 512;
        const unsigned short* src = ag + (size_t)(wv * 16 + frow) * NM + t * 32 + fks;
        gld16(src, dst);
        gld16(src + (size_t)128 * NM, dst + 8 * 512);
    };
    auto stageB = [&](int t, int buf) {
        unsigned short* dst = lds + buf * 16384 + 8192 + wv * 512;
        const unsigned short* src = bg + (size_t)(wv * 16 + frow) * NM + t * 32 + fks;
        gld16(src, dst);
        gld16(src + (size_t)128 * NM, dst + 8 * 512);
    };

    auto body = [&](int buf) {
        const unsigned short* bA = lds + buf * 16384;
        const unsigned short* bB = bA + 8192;
        bf16x8 af[4], bf[4];
#pragma unroll
        for (int m = 0; m < 4; ++m)
            af[m] = *(const bf16x8*)(bA + (wr * 8 + m) * 512 + la);
#pragma unroll
        for (int n = 0; n < 4; ++n)
            bf[n] = *(const bf16x8*)(bB + (wc * 4 + n) * 512 + la);
        __builtin_amdgcn_s_setprio(1);
#pragma unroll
        for (int m = 0; m < 4; ++m)
#pragma unroll
            for (int n = 0; n < 4; ++n)
                acc[m][n] = __builtin_amdgcn_mfma_f32_16x16x32_bf16(af[m], bf[n], acc[m][n], 0, 0, 0);
        __builtin_amdgcn_s_setprio(0);
#pragma unroll
        for (int m = 0; m < 4; ++m)
            af[m] = *(const bf16x8*)(bA + (wr * 8 + 4 + m) * 512 + la);
        __builtin_amdgcn_s_setprio(1);
#pragma unroll
        for (int m = 0; m < 4; ++m)
#pragma unroll
            for (int n = 0; n < 4; ++n)
                acc[4 + m][n] = __builtin_amdgcn_mfma_f32_16x16x32_bf16(af[m], bf[n], acc[4 + m][n], 0, 0, 0);
        __builtin_amdgcn_s_setprio(0);
    };

    const int NKT = NM / 32;               // 64
    stageA(0, 0); stageB(0, 0);

    int buf = 0;
    for (int t = 0; t < NKT; ++t) {
        if (t + 1 < NKT) {
            stageA(t + 1, buf ^ 1);        // prefetch next tile into other buffer
            stageB(t + 1, buf ^ 1);
            WAITV(4);                      // tile t landed; tile t+1 (4 loads) flying
        } else {
            WAITV(0);
        }
        BAR();                             // publish tile t across waves
        body(buf);
        BAR();                             // all reads done before buf restaged
        buf ^= 1;
    }

    // epilogue: N-frags alternate gate(even)/up(odd) with identical lane map
#pragma unroll
    for (int mf = 0; mf < 8; ++mf)
#pragma unroll
        for (int p = 0; p < 2; ++p)
#pragma unroll
            for (int i = 0; i < 4; ++i) {
                const float g = acc[mf][2 * p][i];
                const float u = acc[mf][2 * p + 1][i];
                const float s = g / (1.f + __expf(-g));
                const int r = wr * 128 + mf * 16 + lq * 4 + i;
                const int h = wc * 32 + p * 16 + lr;
                hg[(size_t)r * NH + h] = f2bf(s * u);
            }
}

// ================= GEMM2 (256^2 fine-phase): out = hid * w2T^T =================
// A = hid [E*T][H], B = w2t [E][M][H], K = H, fp32 out. Same 2-buffer pipeline.
__global__ __launch_bounds__(512, 2) void gemm2p_kernel(
        const unsigned short* __restrict__ hid, const unsigned short* __restrict__ w2t,
        float* __restrict__ out) {
    const int tid = threadIdx.x;
    const int lane = tid & 63, wv = tid >> 6;
    const int wr = wv >> 2, wc = wv & 3;
    const int e = blockIdx.y;
    const int d = blockIdx.x;                          // 0..63
    const int l = (d & 7) * 8 + (d >> 3);
    const int mt = l >> 3, tt = l & 7;                 // mtile 0..7, ttile 0..7

    const unsigned short* ag = hid + (size_t)(e * NT + tt * 256) * NH;
    const unsigned short* bg = w2t + (size_t)e * NM * NH + (size_t)(mt * 256) * NH;
    float* og = out + (size_t)(e * NT + tt * 256) * NM + mt * 256;

    __shared__ __align__(16) unsigned short lds[2 * 16384];

    const int frow = lane & 15;
    const int fks  = (lane >> 4) * 8;
    const int la   = lane * 8;
    const int lr   = lane & 15, lq = lane >> 4;

    f32x4 acc[8][4];
#pragma unroll
    for (int m = 0; m < 8; ++m)
#pragma unroll
        for (int n = 0; n < 4; ++n) acc[m][n] = (f32x4){0.f, 0.f, 0.f, 0.f};

    auto stageA = [&](int t, int buf) {
        unsigned short* dst = lds + buf * 16384 + wv * 512;
        const unsigned short* src = ag + (size_t)(wv * 16 + frow) * NH + t * 32 + fks;
        gld16(src, dst);
        gld16(src + (size_t)128 * NH, dst + 8 * 512);
    };
    auto stageB = [&](int t, int buf) {
        unsigned short* dst = lds + buf * 16384 + 8192 + wv * 512;
        const unsigned short* src = bg + (size_t)(wv * 16 + frow) * NH + t * 32 + fks;
        gld16(src, dst);
        gld16(src + (size_t)128 * NH, dst + 8 * 512);
    };

    auto body = [&](int buf) {
        const unsigned short* bA = lds + buf * 16384;
        const unsigned short* bB = bA + 8192;
        bf16x8 af[4], bf[4];
#pragma unroll
        for (int m = 0; m < 4; ++m)
            af[m] = *(const bf16x8*)(bA + (wr * 8 + m) * 512 + la);
#pragma unroll
        for (int n = 0; n < 4; ++n)
            bf[n] = *(const bf16x8*)(bB + (wc * 4 + n) * 512 + la);
        __builtin_amdgcn_s_setprio(1);
#pragma unroll
        for (int m = 0; m < 4; ++m)
#pragma unroll
            for (int n = 0; n < 4; ++n)
                acc[m][n] = __builtin_amdgcn_mfma_f32_16x16x32_bf16(af[m], bf[n], acc[m][n], 0, 0, 0);
        __builtin_amdgcn_s_setprio(0);
#pragma unroll
        for (int m = 0; m < 4; ++m)
            af[m] = *(const bf16x8*)(bA + (wr * 8 + 4 + m) * 512 + la);
        __builtin_amdgcn_s_setprio(1);
#pragma unroll
        for (int m = 0; m < 4; ++m)
#pragma unroll
            for (int n = 0; n < 4; ++n)
                acc[4 + m][n] = __builtin_amdgcn_mfma_f32_16x16x32_bf16(af[m], bf[n], acc[4 + m][n], 0, 0, 0);
        __builtin_amdgcn_s_setprio(0);
    };

    const int NKT = NH / 32;               // 224
    stageA(0, 0); stageB(0, 0);

    int buf = 0;
    for (int t = 0; t < NKT; ++t) {
        if (t + 1 < NKT) {
            stageA(t + 1, buf ^ 1);
            stageB(t + 1, buf ^ 1);
            WAITV(4);
        } else {
            WAITV(0);
        }
        BAR();
        body(buf);
        BAR();
        buf ^= 1;
    }

#pragma unroll
    for (int mf = 0; mf < 8; ++mf)
#pragma unroll
        for (int n = 0; n < 4; ++n)
#pragma unroll
            for (int i = 0; i < 4; ++i) {
                const int r = wr * 128 + mf * 16 + lq * 4 + i;
                const int c = wc * 64 + n * 16 + lr;
                og[(size_t)r * NM + c] = acc[mf][n][i];
            }
}

// ===================== fallback (round-1, fused-convert) =====================
#define ROWB 80
#define TILEB (128 * ROWB)

__global__ __launch_bounds__(256, 2) void gemm1_fb_kernel(
        const float* __restrict__ x, const float* __restrict__ w1,
        const float* __restrict__ w3, unsigned short* __restrict__ hid) {
    const int tid = threadIdx.x;
    const int e = blockIdx.y;
    const int d = blockIdx.x;
    const int l = (d & 7) * 112 + (d >> 3);
    const int hn = l >> 4, tm = l & 15;

    const float* xg  = x  + (size_t)(e * NT + tm * 128) * NM;
    const float* w1g = w1 + (size_t)e * NM * NH + hn * 128;
    const float* w3g = w3 + (size_t)e * NM * NH + hn * 128;
    unsigned short* hg = hid + (size_t)(e * NT + tm * 128) * NH + hn * 128;

    __shared__ __align__(16) unsigned char lds[2 * 3 * TILEB];

    const int a_r = tid >> 3, a_c4 = tid & 7;
    const int w_kq = (tid >> 2) & 7;
    const int w_cg = ((tid >> 5) << 2) | (tid & 3);

    const int lane = tid & 63;
    const int wv = tid >> 6;
    const int r0w = (wv >> 1) * 64, c0w = (wv & 1) * 64;
    const int lr = lane & 15, lq = lane >> 4;

    f32x4 accg[4][4], accu[4][4];
#pragma unroll
    for (int m = 0; m < 4; ++m)
#pragma unroll
        for (int n = 0; n < 4; ++n) {
            accg[m][n] = (f32x4){0.f, 0.f, 0.f, 0.f};
            accu[m][n] = (f32x4){0.f, 0.f, 0.f, 0.f};
        }

    f32x4 la0, la1, la2, la3;
    f32x4 l10, l11, l12, l13, l30, l31, l32, l33;

    auto stage_load = [&](int ks) {
        const int k0 = ks * 32;
        const float* pa = xg + (size_t)a_r * NM + k0 + a_c4 * 4;
        la0 = *(const f32x4*)(pa);
        la1 = *(const f32x4*)(pa + 32 * NM);
        la2 = *(const f32x4*)(pa + 64 * NM);
        la3 = *(const f32x4*)(pa + 96 * NM);
        const float* p1 = w1g + (size_t)(k0 + w_kq * 4) * NH + w_cg * 4;
        l10 = *(const f32x4*)(p1);
        l11 = *(const f32x4*)(p1 + NH);
        l12 = *(const f32x4*)(p1 + 2 * NH);
        l13 = *(const f32x4*)(p1 + 3 * NH);
        const float* p3 = w3g + (size_t)(k0 + w_kq * 4) * NH + w_cg * 4;
        l30 = *(const f32x4*)(p3);
        l31 = *(const f32x4*)(p3 + NH);
        l32 = *(const f32x4*)(p3 + 2 * NH);
        l33 = *(const f32x4*)(p3 + 3 * NH);
    };

    auto stage_write = [&](int buf) {
        unsigned char* base = lds + buf * (3 * TILEB);
        unsigned char* pa = base + a_r * ROWB + a_c4 * 8;
        *(u16x4*)(pa)             = (u16x4){f2bf(la0[0]), f2bf(la0[1]), f2bf(la0[2]), f2bf(la0[3])};
        *(u16x4*)(pa + 32 * ROWB) = (u16x4){f2bf(la1[0]), f2bf(la1[1]), f2bf(la1[2]), f2bf(la1[3])};
        *(u16x4*)(pa + 64 * ROWB) = (u16x4){f2bf(la2[0]), f2bf(la2[1]), f2bf(la2[2]), f2bf(la2[3])};
        *(u16x4*)(pa + 96 * ROWB) = (u16x4){f2bf(la3[0]), f2bf(la3[1]), f2bf(la3[2]), f2bf(la3[3])};
        unsigned char* pw1 = base + TILEB + w_kq * 8;
#pragma unroll
        for (int j = 0; j < 4; ++j) {
            const int c = w_cg * 4 + j;
            *(u16x4*)(pw1 + c * ROWB) =
                (u16x4){f2bf(l10[j]), f2bf(l11[j]), f2bf(l12[j]), f2bf(l13[j])};
        }
        unsigned char* pw3 = base + 2 * TILEB + w_kq * 8;
#pragma unroll
        for (int j = 0; j < 4; ++j) {
            const int c = w_cg * 4 + j;
            *(u16x4*)(pw3 + c * ROWB) =
                (u16x4){f2bf(l30[j]), f2bf(l31[j]), f2bf(l32[j]), f2bf(l33[j])};
        }
    };

    auto compute = [&](int buf) {
        const unsigned char* base = lds + buf * (3 * TILEB);
        bf16x8 af[4], b1f[4], b3f[4];
#pragma unroll
        for (int m = 0; m < 4; ++m)
            af[m] = *(const bf16x8*)(base + (r0w + m * 16 + lr) * ROWB + lq * 16);
#pragma unroll
        for (int n = 0; n < 4; ++n) {
            b1f[n] = *(const bf16x8*)(base + TILEB + (c0w + n * 16 + lr) * ROWB + lq * 16);
            b3f[n] = *(const bf16x8*)(base + 2 * TILEB + (c0w + n * 16 + lr) * ROWB + lq * 16);
        }
#pragma unroll
        for (int m = 0; m < 4; ++m)
#pragma unroll
            for (int n = 0; n < 4; ++n) {
                accg[m][n] = __builtin_amdgcn_mfma_f32_16x16x32_bf16(af[m], b1f[n], accg[m][n], 0, 0, 0);
                accu[m][n] = __builtin_amdgcn_mfma_f32_16x16x32_bf16(af[m], b3f[n], accu[m][n], 0, 0, 0);
            }
    };

    stage_load(0);
    stage_write(0);
    __syncthreads();
    int cur = 0;
    const int NK = NM / 32;
    for (int ks = 0; ks < NK; ++ks) {
        const bool more = (ks + 1 < NK);
        if (more) stage_load(ks + 1);
        compute(cur);
        if (more) {
            stage_write(cur ^ 1);
            __syncthreads();
        }
        cur ^= 1;
    }

#pragma unroll
    for (int m = 0; m < 4; ++m)
#pragma unroll
        for (int n = 0; n < 4; ++n)
#pragma unroll
            for (int i = 0; i < 4; ++i) {
                const float g = accg[m][n][i];
                const float u = accu[m][n][i];
                const float s = g / (1.f + __expf(-g));
                const int r = r0w + m * 16 + lq * 4 + i;
                const int c = c0w + n * 16 + lr;
                hg[(size_t)r * NH + c] = f2bf(s * u);
            }
}

__global__ __launch_bounds__(256, 2) void gemm2_fb_kernel(
        const unsigned short* __restrict__ hid, const float* __restrict__ w2,
        float* __restrict__ out) {
    const int tid = threadIdx.x;
    const int e = blockIdx.y;
    const int d = blockIdx.x;
    const int l = (d & 7) * 32 + (d >> 3);
    const int mn = l >> 4, tm = l & 15;

    const unsigned short* ag = hid + (size_t)(e * NT + tm * 128) * NH;
    const float* wg = w2 + (size_t)e * NH * NM + mn * 128;
    float* og = out + (size_t)(e * NT + tm * 128) * NM + mn * 128;

    __shared__ __align__(16) unsigned char lds[2 * 2 * TILEB];

    const int a_row = tid >> 2, a_ch = tid & 3;
    const int w_kq = (tid >> 2) & 7;
    const int w_cg = ((tid >> 5) << 2) | (tid & 3);

    const int lane = tid & 63;
    const int wv = tid >> 6;
    const int r0w = (wv >> 1) * 64, c0w = (wv & 1) * 64;
    const int lr = lane & 15, lq = lane >> 4;

    f32x4 acc[4][4];
#pragma unroll
    for (int m = 0; m < 4; ++m)
#pragma unroll
        for (int n = 0; n < 4; ++n) acc[m][n] = (f32x4){0.f, 0.f, 0.f, 0.f};

    u32x4 lau0, lau1;
    f32x4 lw0, lw1, lw2, lw3;

    auto stage_load = [&](int ks) {
        const int k0 = ks * 32;
        lau0 = *(const u32x4*)(ag + (size_t)a_row * NH + k0 + a_ch * 8);
        lau1 = *(const u32x4*)(ag + (size_t)(a_row + 64) * NH + k0 + a_ch * 8);
        const float* p = wg + (size_t)(k0 + w_kq * 4) * NM + w_cg * 4;
        lw0 = *(const f32x4*)(p);
        lw1 = *(const f32x4*)(p + NM);
        lw2 = *(const f32x4*)(p + 2 * NM);
        lw3 = *(const f32x4*)(p + 3 * NM);
    };

    auto stage_write = [&](int buf) {
        unsigned char* base = lds + buf * (2 * TILEB);
        *(u32x4*)(base + a_row * ROWB + a_ch * 16) = lau0;
        *(u32x4*)(base + (a_row + 64) * ROWB + a_ch * 16) = lau1;
        unsigned char* pw = base + TILEB + w_kq * 8;
#pragma unroll
        for (int j = 0; j < 4; ++j) {
            const int c = w_cg * 4 + j;
            *(u16x4*)(pw + c * ROWB) =
                (u16x4){f2bf(lw0[j]), f2bf(lw1[j]), f2bf(lw2[j]), f2bf(lw3[j])};
        }
    };

    auto compute = [&](int buf) {
        const unsigned char* base = lds + buf * (2 * TILEB);
        bf16x8 af[4], bf[4];
#pragma unroll
        for (int m = 0; m < 4; ++m)
            af[m] = *(const bf16x8*)(base + (r0w + m * 16 + lr) * ROWB + lq * 16);
#pragma unroll
        for (int n = 0; n < 4; ++n)
            bf[n] = *(const bf16x8*)(base + TILEB + (c0w + n * 16 + lr) * ROWB + lq * 16);
#pragma unroll
        for (int m = 0; m < 4; ++m)
#pragma unroll
            for (int n = 0; n < 4; ++n)
                acc[m][n] = __builtin_amdgcn_mfma_f32_16x16x32_bf16(af[m], bf[n], acc[m][n], 0, 0, 0);
    };

    stage_load(0);
    stage_write(0);
    __syncthreads();
    int cur = 0;
    const int NK = NH / 32;
    for (int ks = 0; ks < NK; ++ks) {
        const bool more = (ks + 1 < NK);
        if (more) stage_load(ks + 1);
        compute(cur);
        if (more) {
            stage_write(cur ^ 1);
            __syncthreads();
        }
        cur ^= 1;
    }

#pragma unroll
    for (int m = 0; m < 4; ++m)
#pragma unroll
        for (int n = 0; n < 4; ++n)
#pragma unroll
            for (int i = 0; i < 4; ++i) {
                const int r = r0w + m * 16 + lq * 4 + i;
                const int c = c0w + n * 16 + lr;
                og[(size_t)r * NM + c] = acc[m][n][i];
            }
}

// ================================ launcher ================================

extern "C" void kernel_launch(void* const* d_in, const int* in_sizes, int n_in,
                              void* d_out, int out_size, void* d_ws, size_t ws_size,
                              hipStream_t stream) {
    const float* x  = (const float*)d_in[0];
    const float* w1 = (const float*)d_in[1];
    const float* w2 = (const float*)d_in[2];
    const float* w3 = (const float*)d_in[3];
    float* out = (float*)d_out;

    const size_t XB_SZ   = (size_t)NE * NT * NM * 2;        //  64 MiB
    const size_t WCAT_SZ = (size_t)NE * 2 * NH * NM * 2;    // 448 MiB
    const size_t HID_SZ  = (size_t)NE * NT * NH * 2;        // 224 MiB
    const size_t NEED = XB_SZ + WCAT_SZ + HID_SZ;           // 736 MiB

    if (ws_size >= NEED) {
        unsigned char* ws = (unsigned char*)d_ws;
        unsigned short* xbp  = (unsigned short*)(ws);
        unsigned short* wcat = (unsigned short*)(ws + XB_SZ);
        unsigned short* hidb = (unsigned short*)(ws + XB_SZ + WCAT_SZ);
        unsigned short* w2t  = (unsigned short*)(ws);   // reuses xb/wcat after gemm1

        convert_x_kernel<<<dim3((NE * NT * NM) / 1024), 256, 0, stream>>>(x, xbp);
        convert_w13_kernel<<<dim3((NM / 64) * (NH / 64), NE), 256, 0, stream>>>(w1, w3, wcat);
        gemm1p_kernel<<<dim3(448, NE), 512, 0, stream>>>(xbp, wcat, hidb);
        convert_wT_kernel<<<dim3((NH / 64) * (NM / 64), NE), 256, 0, stream>>>(w2, w2t, NH, NM);
        gemm2p_kernel<<<dim3(64, NE), 512, 0, stream>>>(hidb, w2t, out);
    } else {
        unsigned short* hid = (unsigned short*)d_ws;
        gemm1_fb_kernel<<<dim3(896, NE), 256, 0, stream>>>(x, w1, w3, hid);
        gemm2_fb_kernel<<<dim3(256, NE), 256, 0, stream>>>(hid, w2, out);
    }
}

// Round 11
// 1952.456 us; speedup vs baseline: 1.4831x; 1.0291x over previous
//
#include <hip/hip_runtime.h>

typedef __attribute__((ext_vector_type(8))) short bf16x8;
typedef __attribute__((ext_vector_type(4))) float f32x4;
typedef __attribute__((ext_vector_type(4))) unsigned int u32x4;
typedef __attribute__((ext_vector_type(4))) unsigned short u16x4;

#define NE 8
#define NT 2048   // tokens per expert (B*C)
#define NM 2048
#define NH 7168

// Raw barrier (no implicit vmcnt(0) drain) + counted vmcnt waits.
#define BAR() asm volatile("s_barrier" ::: "memory")
#define WAITV(N) asm volatile("s_waitcnt vmcnt(" #N ")" ::: "memory")

__device__ __forceinline__ unsigned short f2bf(float f) {
    unsigned int u = __float_as_uint(f);
    return (unsigned short)((u + 0x7fffu + ((u >> 16) & 1u)) >> 16);  // RNE
}

__device__ __forceinline__ void gld16(const void* g, void* l) {
    __builtin_amdgcn_global_load_lds(
        (const __attribute__((address_space(1))) void*)g,
        (__attribute__((address_space(3))) void*)l, 16, 0, 0);
}

// ============================ conversion kernels ============================

__global__ __launch_bounds__(256) void convert_x_kernel(
        const float* __restrict__ in, unsigned short* __restrict__ out) {
    const int i = blockIdx.x * 256 + threadIdx.x;      // f32x4 index
    f32x4 a = ((const f32x4*)in)[i];
    ((u16x4*)out)[i] = (u16x4){f2bf(a[0]), f2bf(a[1]), f2bf(a[2]), f2bf(a[3])};
}

// w [E][R][C] fp32 -> wT [E][C][R] bf16 (plain transpose), 64x64 LDS tiles.
__global__ __launch_bounds__(256) void convert_wT_kernel(
        const float* __restrict__ in, unsigned short* __restrict__ out,
        int R, int C) {
    const int t = threadIdx.x;
    const int e = blockIdx.y;
    const int tiles_c = C >> 6;
    const int tr = blockIdx.x / tiles_c, tc = blockIdx.x % tiles_c;

    const float* ip = in + (size_t)e * R * C + (size_t)(tr * 64) * C + tc * 64;
    unsigned short* op = out + (size_t)e * R * C + (size_t)(tc * 64) * R + tr * 64;

    __shared__ unsigned short tl[64][68];

    const int rr = t >> 4, c4 = (t & 15) * 4;
#pragma unroll
    for (int q = 0; q < 4; ++q) {
        const int r = q * 16 + rr;
        f32x4 v = *(const f32x4*)(ip + (size_t)r * C + c4);
        *(u16x4*)&tl[r][c4] = (u16x4){f2bf(v[0]), f2bf(v[1]), f2bf(v[2]), f2bf(v[3])};
    }
    __syncthreads();
#pragma unroll
    for (int q = 0; q < 4; ++q) {
        const int oc = q * 16 + rr;          // output row = input col
        u16x4 v = (u16x4){tl[c4][oc], tl[c4 + 1][oc], tl[c4 + 2][oc], tl[c4 + 3][oc]};
        *(u16x4*)(op + (size_t)oc * R + c4) = v;
    }
}

// w1,w3 [E][M][H] fp32 -> wcat [E][2H][M] bf16, transposed + 16-row interleaved:
// wcat row = 32*(h>>4) + 16*which + (h&15), which: 0=w1(gate), 1=w3(up).
__global__ __launch_bounds__(256) void convert_w13_kernel(
        const float* __restrict__ w1, const float* __restrict__ w3,
        unsigned short* __restrict__ wcat) {
    const int t = threadIdx.x;
    const int e = blockIdx.y;
    const int tiles_c = NH >> 6;              // 112
    const int tr = blockIdx.x / tiles_c, tc = blockIdx.x % tiles_c;

    __shared__ unsigned short tl[64][68];
    const int rr = t >> 4, c4 = (t & 15) * 4;
    unsigned short* ob = wcat + (size_t)e * (2 * NH) * NM + (size_t)(tc * 128) * NM + tr * 64;

#pragma unroll
    for (int pass = 0; pass < 2; ++pass) {
        const float* ip = (pass ? w3 : w1) + (size_t)e * NM * NH + (size_t)(tr * 64) * NH + tc * 64;
        if (pass) __syncthreads();            // tl reuse
#pragma unroll
        for (int q = 0; q < 4; ++q) {
            const int r = q * 16 + rr;
            f32x4 v = *(const f32x4*)(ip + (size_t)r * NH + c4);
            *(u16x4*)&tl[r][c4] = (u16x4){f2bf(v[0]), f2bf(v[1]), f2bf(v[2]), f2bf(v[3])};
        }
        __syncthreads();
#pragma unroll
        for (int q = 0; q < 4; ++q) {
            const int oc = q * 16 + rr;       // h within tile
            const int orow = ((oc >> 4) * 32) + pass * 16 + (oc & 15);
            u16x4 v = (u16x4){tl[c4][oc], tl[c4 + 1][oc], tl[c4 + 2][oc], tl[c4 + 3][oc]};
            *(u16x4*)(ob + (size_t)orow * NM + c4) = v;
        }
    }
}

// ========== GEMM1 (256^2, BK=64, 4-phase m201 schedule): hid = silu(g)*u ==========
// A = xb [E*T][M] ; B = wcat [E][2H][M] (gate/up 16-row interleave). Frag-major
// LDS (0-conflict). K-step 64 = kh0+kh1. Phases: {reads, stage, BAR, 16 MFMA,
// [WAITV], BAR} x4. Waits at PHASE ENDS (post-MFMA): ph1-end WAITV(4) => kh1(t)
// landed (read in ph2); ph3-end WAITV(4) => kh0(t+1) landed (read next ph0).
// Ledger: entering iter t, kh1(t):4 in flight; ph0/ph1 issue 4 (kh0(t+1)),
// ph2/ph3 issue 4 (kh1(t+1)); each WAITV(4) retires exactly the needed oldest 4.
// Anti-dep: stages into buf^1 follow prior iter's ph3-end BAR (postdates reads).
__global__ __launch_bounds__(512, 2) void gemm1p_kernel(
        const unsigned short* __restrict__ xb, const unsigned short* __restrict__ wcat,
        unsigned short* __restrict__ hid) {
    const int tid = threadIdx.x;
    const int lane = tid & 63, wv = tid >> 6;          // 8 waves
    const int wr = wv >> 2, wc = wv & 3;               // 2M x 4N
    const int e = blockIdx.y;
    const int d = blockIdx.x;                          // 0..447
    const int l = (d & 7) * 56 + (d >> 3);             // XCD-contiguous (448%8==0)
    const int ct = l >> 3, tt = l & 7;                 // ctile 0..55, ttile 0..7

    const unsigned short* ag = xb   + (size_t)(e * NT + tt * 256) * NM;
    const unsigned short* bg = wcat + (size_t)e * (2 * NH) * NM + (size_t)(ct * 256) * NM;
    unsigned short* hg = hid + (size_t)(e * NT + tt * 256) * NH + ct * 128;

    // 2 buf x (A: 32 frags + B: 32 frags) x 512 shorts = 128 KiB
    __shared__ __align__(16) unsigned short lds[2 * 32768];

    const int frow = lane & 15;            // staging src row within frag
    const int fks  = (lane >> 4) * 8;      // k offset within 32
    const int la   = lane * 8;             // frag-major read: lane*16B
    const int lr   = lane & 15, lq = lane >> 4;

    f32x4 acc[8][4];
#pragma unroll
    for (int m = 0; m < 8; ++m)
#pragma unroll
        for (int n = 0; n < 4; ++n) acc[m][n] = (f32x4){0.f, 0.f, 0.f, 0.f};

    // A frag (kh,f): buf*32768 + (kh*16+f)*512 ; B frag: +16384
    auto stageA = [&](int t, int kh, int buf) {
        unsigned short* dst = lds + buf * 32768 + (kh * 16 + wv) * 512;
        const unsigned short* src = ag + (size_t)(wv * 16 + frow) * NM + t * 64 + kh * 32 + fks;
        gld16(src, dst);
        gld16(src + (size_t)128 * NM, dst + 8 * 512);
    };
    auto stageB = [&](int t, int kh, int buf) {
        unsigned short* dst = lds + buf * 32768 + 16384 + (kh * 16 + wv) * 512;
        const unsigned short* src = bg + (size_t)(wv * 16 + frow) * NM + t * 64 + kh * 32 + fks;
        gld16(src, dst);
        gld16(src + (size_t)128 * NM, dst + 8 * 512);
    };

    const int NKT = NM / 64;               // 32
    // prologue: full tile 0 (8 loads); kh0 landed+published, kh1(0):4 in flight
    stageA(0, 0, 0); stageB(0, 0, 0); stageA(0, 1, 0); stageB(0, 1, 0);
    WAITV(4); BAR();

    for (int t = 0; t < NKT; ++t) {
        const int buf = t & 1, nb = buf ^ 1;
        const bool more = (t + 1 < NKT);
        const unsigned short* bA = lds + buf * 32768;
        const unsigned short* bB = bA + 16384;
        bf16x8 af[4], bfr[4];

        // ---- ph0: kh0, m-lo ----
#pragma unroll
        for (int m = 0; m < 4; ++m) af[m] = *(const bf16x8*)(bA + (wr * 8 + m) * 512 + la);
#pragma unroll
        for (int n = 0; n < 4; ++n) bfr[n] = *(const bf16x8*)(bB + (wc * 4 + n) * 512 + la);
        if (more) stageA(t + 1, 0, nb);
        BAR();
        __builtin_amdgcn_s_setprio(1);
#pragma unroll
        for (int m = 0; m < 4; ++m)
#pragma unroll
            for (int n = 0; n < 4; ++n)
                acc[m][n] = __builtin_amdgcn_mfma_f32_16x16x32_bf16(af[m], bfr[n], acc[m][n], 0, 0, 0);
        __builtin_amdgcn_s_setprio(0);
        BAR();

        // ---- ph1: kh0, m-hi ----
#pragma unroll
        for (int m = 0; m < 4; ++m) af[m] = *(const bf16x8*)(bA + (wr * 8 + 4 + m) * 512 + la);
        if (more) stageB(t + 1, 0, nb);
        BAR();
        __builtin_amdgcn_s_setprio(1);
#pragma unroll
        for (int m = 0; m < 4; ++m)
#pragma unroll
            for (int n = 0; n < 4; ++n)
                acc[4 + m][n] = __builtin_amdgcn_mfma_f32_16x16x32_bf16(af[m], bfr[n], acc[4 + m][n], 0, 0, 0);
        __builtin_amdgcn_s_setprio(0);
        if (more) { WAITV(4); } else { WAITV(0); }   // kh1(t) landed
        BAR();

        // ---- ph2: kh1, m-lo ----
#pragma unroll
        for (int m = 0; m < 4; ++m) af[m] = *(const bf16x8*)(bA + (16 + wr * 8 + m) * 512 + la);
#pragma unroll
        for (int n = 0; n < 4; ++n) bfr[n] = *(const bf16x8*)(bB + (16 + wc * 4 + n) * 512 + la);
        if (more) stageA(t + 1, 1, nb);
        BAR();
        __builtin_amdgcn_s_setprio(1);
#pragma unroll
        for (int m = 0; m < 4; ++m)
#pragma unroll
            for (int n = 0; n < 4; ++n)
                acc[m][n] = __builtin_amdgcn_mfma_f32_16x16x32_bf16(af[m], bfr[n], acc[m][n], 0, 0, 0);
        __builtin_amdgcn_s_setprio(0);
        BAR();

        // ---- ph3: kh1, m-hi ----
#pragma unroll
        for (int m = 0; m < 4; ++m) af[m] = *(const bf16x8*)(bA + (16 + wr * 8 + 4 + m) * 512 + la);
        if (more) stageB(t + 1, 1, nb);
        BAR();
        __builtin_amdgcn_s_setprio(1);
#pragma unroll
        for (int m = 0; m < 4; ++m)
#pragma unroll
            for (int n = 0; n < 4; ++n)
                acc[4 + m][n] = __builtin_amdgcn_mfma_f32_16x16x32_bf16(af[m], bfr[n], acc[4 + m][n], 0, 0, 0);
        __builtin_amdgcn_s_setprio(0);
        if (more) { WAITV(4); }                      // kh0(t+1) landed
        BAR();
    }

    // epilogue: N-frags alternate gate(even)/up(odd) with identical lane map
#pragma unroll
    for (int mf = 0; mf < 8; ++mf)
#pragma unroll
        for (int p = 0; p < 2; ++p)
#pragma unroll
            for (int i = 0; i < 4; ++i) {
                const float g = acc[mf][2 * p][i];
                const float u = acc[mf][2 * p + 1][i];
                const float s = g / (1.f + __expf(-g));
                const int r = wr * 128 + mf * 16 + lq * 4 + i;
                const int h = wc * 32 + p * 16 + lr;
                hg[(size_t)r * NH + h] = f2bf(s * u);
            }
}

// ===== GEMM2 (256^2, BK=64, 4-phase m201 schedule): out = hid * w2T^T =====
__global__ __launch_bounds__(512, 2) void gemm2p_kernel(
        const unsigned short* __restrict__ hid, const unsigned short* __restrict__ w2t,
        float* __restrict__ out) {
    const int tid = threadIdx.x;
    const int lane = tid & 63, wv = tid >> 6;
    const int wr = wv >> 2, wc = wv & 3;
    const int e = blockIdx.y;
    const int d = blockIdx.x;                          // 0..63
    const int l = (d & 7) * 8 + (d >> 3);
    const int mt = l >> 3, tt = l & 7;                 // mtile 0..7, ttile 0..7

    const unsigned short* ag = hid + (size_t)(e * NT + tt * 256) * NH;
    const unsigned short* bg = w2t + (size_t)e * NM * NH + (size_t)(mt * 256) * NH;
    float* og = out + (size_t)(e * NT + tt * 256) * NM + mt * 256;

    __shared__ __align__(16) unsigned short lds[2 * 32768];

    const int frow = lane & 15;
    const int fks  = (lane >> 4) * 8;
    const int la   = lane * 8;
    const int lr   = lane & 15, lq = lane >> 4;

    f32x4 acc[8][4];
#pragma unroll
    for (int m = 0; m < 8; ++m)
#pragma unroll
        for (int n = 0; n < 4; ++n) acc[m][n] = (f32x4){0.f, 0.f, 0.f, 0.f};

    auto stageA = [&](int t, int kh, int buf) {
        unsigned short* dst = lds + buf * 32768 + (kh * 16 + wv) * 512;
        const unsigned short* src = ag + (size_t)(wv * 16 + frow) * NH + t * 64 + kh * 32 + fks;
        gld16(src, dst);
        gld16(src + (size_t)128 * NH, dst + 8 * 512);
    };
    auto stageB = [&](int t, int kh, int buf) {
        unsigned short* dst = lds + buf * 32768 + 16384 + (kh * 16 + wv) * 512;
        const unsigned short* src = bg + (size_t)(wv * 16 + frow) * NH + t * 64 + kh * 32 + fks;
        gld16(src, dst);
        gld16(src + (size_t)128 * NH, dst + 8 * 512);
    };

    const int NKT = NH / 64;               // 112
    stageA(0, 0, 0); stageB(0, 0, 0); stageA(0, 1, 0); stageB(0, 1, 0);
    WAITV(4); BAR();

    for (int t = 0; t < NKT; ++t) {
        const int buf = t & 1, nb = buf ^ 1;
        const bool more = (t + 1 < NKT);
        const unsigned short* bA = lds + buf * 32768;
        const unsigned short* bB = bA + 16384;
        bf16x8 af[4], bfr[4];

        // ph0
#pragma unroll
        for (int m = 0; m < 4; ++m) af[m] = *(const bf16x8*)(bA + (wr * 8 + m) * 512 + la);
#pragma unroll
        for (int n = 0; n < 4; ++n) bfr[n] = *(const bf16x8*)(bB + (wc * 4 + n) * 512 + la);
        if (more) stageA(t + 1, 0, nb);
        BAR();
        __builtin_amdgcn_s_setprio(1);
#pragma unroll
        for (int m = 0; m < 4; ++m)
#pragma unroll
            for (int n = 0; n < 4; ++n)
                acc[m][n] = __builtin_amdgcn_mfma_f32_16x16x32_bf16(af[m], bfr[n], acc[m][n], 0, 0, 0);
        __builtin_amdgcn_s_setprio(0);
        BAR();

        // ph1
#pragma unroll
        for (int m = 0; m < 4; ++m) af[m] = *(const bf16x8*)(bA + (wr * 8 + 4 + m) * 512 + la);
        if (more) stageB(t + 1, 0, nb);
        BAR();
        __builtin_amdgcn_s_setprio(1);
#pragma unroll
        for (int m = 0; m < 4; ++m)
#pragma unroll
            for (int n = 0; n < 4; ++n)
                acc[4 + m][n] = __builtin_amdgcn_mfma_f32_16x16x32_bf16(af[m], bfr[n], acc[4 + m][n], 0, 0, 0);
        __builtin_amdgcn_s_setprio(0);
        if (more) { WAITV(4); } else { WAITV(0); }
        BAR();

        // ph2
#pragma unroll
        for (int m = 0; m < 4; ++m) af[m] = *(const bf16x8*)(bA + (16 + wr * 8 + m) * 512 + la);
#pragma unroll
        for (int n = 0; n < 4; ++n) bfr[n] = *(const bf16x8*)(bB + (16 + wc * 4 + n) * 512 + la);
        if (more) stageA(t + 1, 1, nb);
        BAR();
        __builtin_amdgcn_s_setprio(1);
#pragma unroll
        for (int m = 0; m < 4; ++m)
#pragma unroll
            for (int n = 0; n < 4; ++n)
                acc[m][n] = __builtin_amdgcn_mfma_f32_16x16x32_bf16(af[m], bfr[n], acc[m][n], 0, 0, 0);
        __builtin_amdgcn_s_setprio(0);
        BAR();

        // ph3
#pragma unroll
        for (int m = 0; m < 4; ++m) af[m] = *(const bf16x8*)(bA + (16 + wr * 8 + 4 + m) * 512 + la);
        if (more) stageB(t + 1, 1, nb);
        BAR();
        __builtin_amdgcn_s_setprio(1);
#pragma unroll
        for (int m = 0; m < 4; ++m)
#pragma unroll
            for (int n = 0; n < 4; ++n)
                acc[4 + m][n] = __builtin_amdgcn_mfma_f32_16x16x32_bf16(af[m], bfr[n], acc[4 + m][n], 0, 0, 0);
        __builtin_amdgcn_s_setprio(0);
        if (more) { WAITV(4); }
        BAR();
    }

#pragma unroll
    for (int mf = 0; mf < 8; ++mf)
#pragma unroll
        for (int n = 0; n < 4; ++n)
#pragma unroll
            for (int i = 0; i < 4; ++i) {
                const int r = wr * 128 + mf * 16 + lq * 4 + i;
                const int c = wc * 64 + n * 16 + lr;
                og[(size_t)r * NM + c] = acc[mf][n][i];
            }
}

// ===================== fallback (round-1, fused-convert) =====================
#define ROWB 80
#define TILEB (128 * ROWB)

__global__ __launch_bounds__(256, 2) void gemm1_fb_kernel(
        const float* __restrict__ x, const float* __restrict__ w1,
        const float* __restrict__ w3, unsigned short* __restrict__ hid) {
    const int tid = threadIdx.x;
    const int e = blockIdx.y;
    const int d = blockIdx.x;
    const int l = (d & 7) * 112 + (d >> 3);
    const int hn = l >> 4, tm = l & 15;

    const float* xg  = x  + (size_t)(e * NT + tm * 128) * NM;
    const float* w1g = w1 + (size_t)e * NM * NH + hn * 128;
    const float* w3g = w3 + (size_t)e * NM * NH + hn * 128;
    unsigned short* hg = hid + (size_t)(e * NT + tm * 128) * NH + hn * 128;

    __shared__ __align__(16) unsigned char lds[2 * 3 * TILEB];

    const int a_r = tid >> 3, a_c4 = tid & 7;
    const int w_kq = (tid >> 2) & 7;
    const int w_cg = ((tid >> 5) << 2) | (tid & 3);

    const int lane = tid & 63;
    const int wv = tid >> 6;
    const int r0w = (wv >> 1) * 64, c0w = (wv & 1) * 64;
    const int lr = lane & 15, lq = lane >> 4;

    f32x4 accg[4][4], accu[4][4];
#pragma unroll
    for (int m = 0; m < 4; ++m)
#pragma unroll
        for (int n = 0; n < 4; ++n) {
            accg[m][n] = (f32x4){0.f, 0.f, 0.f, 0.f};
            accu[m][n] = (f32x4){0.f, 0.f, 0.f, 0.f};
        }

    f32x4 la0, la1, la2, la3;
    f32x4 l10, l11, l12, l13, l30, l31, l32, l33;

    auto stage_load = [&](int ks) {
        const int k0 = ks * 32;
        const float* pa = xg + (size_t)a_r * NM + k0 + a_c4 * 4;
        la0 = *(const f32x4*)(pa);
        la1 = *(const f32x4*)(pa + 32 * NM);
        la2 = *(const f32x4*)(pa + 64 * NM);
        la3 = *(const f32x4*)(pa + 96 * NM);
        const float* p1 = w1g + (size_t)(k0 + w_kq * 4) * NH + w_cg * 4;
        l10 = *(const f32x4*)(p1);
        l11 = *(const f32x4*)(p1 + NH);
        l12 = *(const f32x4*)(p1 + 2 * NH);
        l13 = *(const f32x4*)(p1 + 3 * NH);
        const float* p3 = w3g + (size_t)(k0 + w_kq * 4) * NH + w_cg * 4;
        l30 = *(const f32x4*)(p3);
        l31 = *(const f32x4*)(p3 + NH);
        l32 = *(const f32x4*)(p3 + 2 * NH);
        l33 = *(const f32x4*)(p3 + 3 * NH);
    };

    auto stage_write = [&](int buf) {
        unsigned char* base = lds + buf * (3 * TILEB);
        unsigned char* pa = base + a_r * ROWB + a_c4 * 8;
        *(u16x4*)(pa)             = (u16x4){f2bf(la0[0]), f2bf(la0[1]), f2bf(la0[2]), f2bf(la0[3])};
        *(u16x4*)(pa + 32 * ROWB) = (u16x4){f2bf(la1[0]), f2bf(la1[1]), f2bf(la1[2]), f2bf(la1[3])};
        *(u16x4*)(pa + 64 * ROWB) = (u16x4){f2bf(la2[0]), f2bf(la2[1]), f2bf(la2[2]), f2bf(la2[3])};
        *(u16x4*)(pa + 96 * ROWB) = (u16x4){f2bf(la3[0]), f2bf(la3[1]), f2bf(la3[2]), f2bf(la3[3])};
        unsigned char* pw1 = base + TILEB + w_kq * 8;
#pragma unroll
        for (int j = 0; j < 4; ++j) {
            const int c = w_cg * 4 + j;
            *(u16x4*)(pw1 + c * ROWB) =
                (u16x4){f2bf(l10[j]), f2bf(l11[j]), f2bf(l12[j]), f2bf(l13[j])};
        }
        unsigned char* pw3 = base + 2 * TILEB + w_kq * 8;
#pragma unroll
        for (int j = 0; j < 4; ++j) {
            const int c = w_cg * 4 + j;
            *(u16x4*)(pw3 + c * ROWB) =
                (u16x4){f2bf(l30[j]), f2bf(l31[j]), f2bf(l32[j]), f2bf(l33[j])};
        }
    };

    auto compute = [&](int buf) {
        const unsigned char* base = lds + buf * (3 * TILEB);
        bf16x8 af[4], b1f[4], b3f[4];
#pragma unroll
        for (int m = 0; m < 4; ++m)
            af[m] = *(const bf16x8*)(base + (r0w + m * 16 + lr) * ROWB + lq * 16);
#pragma unroll
        for (int n = 0; n < 4; ++n) {
            b1f[n] = *(const bf16x8*)(base + TILEB + (c0w + n * 16 + lr) * ROWB + lq * 16);
            b3f[n] = *(const bf16x8*)(base + 2 * TILEB + (c0w + n * 16 + lr) * ROWB + lq * 16);
        }
#pragma unroll
        for (int m = 0; m < 4; ++m)
#pragma unroll
            for (int n = 0; n < 4; ++n) {
                accg[m][n] = __builtin_amdgcn_mfma_f32_16x16x32_bf16(af[m], b1f[n], accg[m][n], 0, 0, 0);
                accu[m][n] = __builtin_amdgcn_mfma_f32_16x16x32_bf16(af[m], b3f[n], accu[m][n], 0, 0, 0);
            }
    };

    stage_load(0);
    stage_write(0);
    __syncthreads();
    int cur = 0;
    const int NK = NM / 32;
    for (int ks = 0; ks < NK; ++ks) {
        const bool more = (ks + 1 < NK);
        if (more) stage_load(ks + 1);
        compute(cur);
        if (more) {
            stage_write(cur ^ 1);
            __syncthreads();
        }
        cur ^= 1;
    }

#pragma unroll
    for (int m = 0; m < 4; ++m)
#pragma unroll
        for (int n = 0; n < 4; ++n)
#pragma unroll
            for (int i = 0; i < 4; ++i) {
                const float g = accg[m][n][i];
                const float u = accu[m][n][i];
                const float s = g / (1.f + __expf(-g));
                const int r = r0w + m * 16 + lq * 4 + i;
                const int c = c0w + n * 16 + lr;
                hg[(size_t)r * NH + c] = f2bf(s * u);
            }
}

__global__ __launch_bounds__(256, 2) void gemm2_fb_kernel(
        const unsigned short* __restrict__ hid, const float* __restrict__ w2,
        float* __restrict__ out) {
    const int tid = threadIdx.x;
    const int e = blockIdx.y;
    const int d = blockIdx.x;
    const int l = (d & 7) * 32 + (d >> 3);
    const int mn = l >> 4, tm = l & 15;

    const unsigned short* ag = hid + (size_t)(e * NT + tm * 128) * NH;
    const float* wg = w2 + (size_t)e * NH * NM + mn * 128;
    float* og = out + (size_t)(e * NT + tm * 128) * NM + mn * 128;

    __shared__ __align__(16) unsigned char lds[2 * 2 * TILEB];

    const int a_row = tid >> 2, a_ch = tid & 3;
    const int w_kq = (tid >> 2) & 7;
    const int w_cg = ((tid >> 5) << 2) | (tid & 3);

    const int lane = tid & 63;
    const int wv = tid >> 6;
    const int r0w = (wv >> 1) * 64, c0w = (wv & 1) * 64;
    const int lr = lane & 15, lq = lane >> 4;

    f32x4 acc[4][4];
#pragma unroll
    for (int m = 0; m < 4; ++m)
#pragma unroll
        for (int n = 0; n < 4; ++n) acc[m][n] = (f32x4){0.f, 0.f, 0.f, 0.f};

    u32x4 lau0, lau1;
    f32x4 lw0, lw1, lw2, lw3;

    auto stage_load = [&](int ks) {
        const int k0 = ks * 32;
        lau0 = *(const u32x4*)(ag + (size_t)a_row * NH + k0 + a_ch * 8);
        lau1 = *(const u32x4*)(ag + (size_t)(a_row + 64) * NH + k0 + a_ch * 8);
        const float* p = wg + (size_t)(k0 + w_kq * 4) * NM + w_cg * 4;
        lw0 = *(const f32x4*)(p);
        lw1 = *(const f32x4*)(p + NM);
        lw2 = *(const f32x4*)(p + 2 * NM);
        lw3 = *(const f32x4*)(p + 3 * NM);
    };

    auto stage_write = [&](int buf) {
        unsigned char* base = lds + buf * (2 * TILEB);
        *(u32x4*)(base + a_row * ROWB + a_ch * 16) = lau0;
        *(u32x4*)(base + (a_row + 64) * ROWB + a_ch * 16) = lau1;
        unsigned char* pw = base + TILEB + w_kq * 8;
#pragma unroll
        for (int j = 0; j < 4; ++j) {
            const int c = w_cg * 4 + j;
            *(u16x4*)(pw + c * ROWB) =
                (u16x4){f2bf(lw0[j]), f2bf(lw1[j]), f2bf(lw2[j]), f2bf(lw3[j])};
        }
    };

    auto compute = [&](int buf) {
        const unsigned char* base = lds + buf * (2 * TILEB);
        bf16x8 af[4], bf[4];
#pragma unroll
        for (int m = 0; m < 4; ++m)
            af[m] = *(const bf16x8*)(base + (r0w + m * 16 + lr) * ROWB + lq * 16);
#pragma unroll
        for (int n = 0; n < 4; ++n)
            bf[n] = *(const bf16x8*)(base + TILEB + (c0w + n * 16 + lr) * ROWB + lq * 16);
#pragma unroll
        for (int m = 0; m < 4; ++m)
#pragma unroll
            for (int n = 0; n < 4; ++n)
                acc[m][n] = __builtin_amdgcn_mfma_f32_16x16x32_bf16(af[m], bf[n], acc[m][n], 0, 0, 0);
    };

    stage_load(0);
    stage_write(0);
    __syncthreads();
    int cur = 0;
    const int NK = NH / 32;
    for (int ks = 0; ks < NK; ++ks) {
        const bool more = (ks + 1 < NK);
        if (more) stage_load(ks + 1);
        compute(cur);
        if (more) {
            stage_write(cur ^ 1);
            __syncthreads();
        }
        cur ^= 1;
    }

#pragma unroll
    for (int m = 0; m < 4; ++m)
#pragma unroll
        for (int n = 0; n < 4; ++n)
#pragma unroll
            for (int i = 0; i < 4; ++i) {
                const int r = r0w + m * 16 + lq * 4 + i;
                const int c = c0w + n * 16 + lr;
                og[(size_t)r * NM + c] = acc[m][n][i];
            }
}

// ================================ launcher ================================

extern "C" void kernel_launch(void* const* d_in, const int* in_sizes, int n_in,
                              void* d_out, int out_size, void* d_ws, size_t ws_size,
                              hipStream_t stream) {
    const float* x  = (const float*)d_in[0];
    const float* w1 = (const float*)d_in[1];
    const float* w2 = (const float*)d_in[2];
    const float* w3 = (const float*)d_in[3];
    float* out = (float*)d_out;

    const size_t XB_SZ   = (size_t)NE * NT * NM * 2;        //  64 MiB
    const size_t WCAT_SZ = (size_t)NE * 2 * NH * NM * 2;    // 448 MiB
    const size_t HID_SZ  = (size_t)NE * NT * NH * 2;        // 224 MiB
    const size_t NEED = XB_SZ + WCAT_SZ + HID_SZ;           // 736 MiB

    if (ws_size >= NEED) {
        unsigned char* ws = (unsigned char*)d_ws;
        unsigned short* xbp  = (unsigned short*)(ws);
        unsigned short* wcat = (unsigned short*)(ws + XB_SZ);
        unsigned short* hidb = (unsigned short*)(ws + XB_SZ + WCAT_SZ);
        unsigned short* w2t  = (unsigned short*)(ws);   // reuses xb/wcat after gemm1

        convert_x_kernel<<<dim3((NE * NT * NM) / 1024), 256, 0, stream>>>(x, xbp);
        convert_w13_kernel<<<dim3((NM / 64) * (NH / 64), NE), 256, 0, stream>>>(w1, w3, wcat);
        gemm1p_kernel<<<dim3(448, NE), 512, 0, stream>>>(xbp, wcat, hidb);
        convert_wT_kernel<<<dim3((NH / 64) * (NM / 64), NE), 256, 0, stream>>>(w2, w2t, NH, NM);
        gemm2p_kernel<<<dim3(64, NE), 512, 0, stream>>>(hidb, w2t, out);
    } else {
        unsigned short* hid = (unsigned short*)d_ws;
        gemm1_fb_kernel<<<dim3(896, NE), 256, 0, stream>>>(x, w1, w3, hid);
        gemm2_fb_kernel<<<dim3(256, NE), 256, 0, stream>>>(hid, w2, out);
    }
}

// Round 12
// 1931.828 us; speedup vs baseline: 1.4989x; 1.0107x over previous
//
#include <hip/hip_runtime.h>

typedef __attribute__((ext_vector_type(8))) short bf16x8;
typedef __attribute__((ext_vector_type(4))) float f32x4;
typedef __attribute__((ext_vector_type(4))) unsigned int u32x4;
typedef __attribute__((ext_vector_type(4))) unsigned short u16x4;

#define NE 8
#define NT 2048   // tokens per expert (B*C)
#define NM 2048
#define NH 7168

// Raw barrier (no implicit vmcnt(0) drain) + counted vmcnt waits.
#define BAR() asm volatile("s_barrier" ::: "memory")
#define WAITV(N) asm volatile("s_waitcnt vmcnt(" #N ")" ::: "memory")

__device__ __forceinline__ unsigned short f2bf(float f) {
    unsigned int u = __float_as_uint(f);
    return (unsigned short)((u + 0x7fffu + ((u >> 16) & 1u)) >> 16);  // RNE
}

__device__ __forceinline__ void gld16(const void* g, void* l) {
    __builtin_amdgcn_global_load_lds(
        (const __attribute__((address_space(1))) void*)g,
        (__attribute__((address_space(3))) void*)l, 16, 0, 0);
}

// ============================ conversion kernels ============================

__global__ __launch_bounds__(256) void convert_x_kernel(
        const float* __restrict__ in, unsigned short* __restrict__ out) {
    const int i = blockIdx.x * 256 + threadIdx.x;      // f32x4 index
    f32x4 a = ((const f32x4*)in)[i];
    ((u16x4*)out)[i] = (u16x4){f2bf(a[0]), f2bf(a[1]), f2bf(a[2]), f2bf(a[3])};
}

// w [E][R][C] fp32 -> wT [E][C][R] bf16 (plain transpose), 64x64 LDS tiles.
__global__ __launch_bounds__(256) void convert_wT_kernel(
        const float* __restrict__ in, unsigned short* __restrict__ out,
        int R, int C) {
    const int t = threadIdx.x;
    const int e = blockIdx.y;
    const int tiles_c = C >> 6;
    const int tr = blockIdx.x / tiles_c, tc = blockIdx.x % tiles_c;

    const float* ip = in + (size_t)e * R * C + (size_t)(tr * 64) * C + tc * 64;
    unsigned short* op = out + (size_t)e * R * C + (size_t)(tc * 64) * R + tr * 64;

    __shared__ unsigned short tl[64][68];

    const int rr = t >> 4, c4 = (t & 15) * 4;
#pragma unroll
    for (int q = 0; q < 4; ++q) {
        const int r = q * 16 + rr;
        f32x4 v = *(const f32x4*)(ip + (size_t)r * C + c4);
        *(u16x4*)&tl[r][c4] = (u16x4){f2bf(v[0]), f2bf(v[1]), f2bf(v[2]), f2bf(v[3])};
    }
    __syncthreads();
#pragma unroll
    for (int q = 0; q < 4; ++q) {
        const int oc = q * 16 + rr;          // output row = input col
        u16x4 v = (u16x4){tl[c4][oc], tl[c4 + 1][oc], tl[c4 + 2][oc], tl[c4 + 3][oc]};
        *(u16x4*)(op + (size_t)oc * R + c4) = v;
    }
}

// w1,w3 [E][M][H] fp32 -> wcat [E][2H][M] bf16, transposed + 16-row interleaved:
// wcat row = 32*(h>>4) + 16*which + (h&15), which: 0=w1(gate), 1=w3(up).
__global__ __launch_bounds__(256) void convert_w13_kernel(
        const float* __restrict__ w1, const float* __restrict__ w3,
        unsigned short* __restrict__ wcat) {
    const int t = threadIdx.x;
    const int e = blockIdx.y;
    const int tiles_c = NH >> 6;              // 112
    const int tr = blockIdx.x / tiles_c, tc = blockIdx.x % tiles_c;

    __shared__ unsigned short tl[64][68];
    const int rr = t >> 4, c4 = (t & 15) * 4;
    unsigned short* ob = wcat + (size_t)e * (2 * NH) * NM + (size_t)(tc * 128) * NM + tr * 64;

#pragma unroll
    for (int pass = 0; pass < 2; ++pass) {
        const float* ip = (pass ? w3 : w1) + (size_t)e * NM * NH + (size_t)(tr * 64) * NH + tc * 64;
        if (pass) __syncthreads();            // tl reuse
#pragma unroll
        for (int q = 0; q < 4; ++q) {
            const int r = q * 16 + rr;
            f32x4 v = *(const f32x4*)(ip + (size_t)r * NH + c4);
            *(u16x4*)&tl[r][c4] = (u16x4){f2bf(v[0]), f2bf(v[1]), f2bf(v[2]), f2bf(v[3])};
        }
        __syncthreads();
#pragma unroll
        for (int q = 0; q < 4; ++q) {
            const int oc = q * 16 + rr;       // h within tile
            const int orow = ((oc >> 4) * 32) + pass * 16 + (oc & 15);
            u16x4 v = (u16x4){tl[c4][oc], tl[c4 + 1][oc], tl[c4 + 2][oc], tl[c4 + 3][oc]};
            *(u16x4*)(ob + (size_t)orow * NM + c4) = v;
        }
    }
}

// ====== GEMM1 (R8 structure, best measured 1081us) + fused w2-transpose ======
// Blocks d<448: gemm1 (256^2, 8 waves, BK=32, frag-major LDS, 3-buf depth-2
// counted-vmcnt pipeline; publish: WAITV->BAR->reads; anti-dep: end BAR).
// Blocks d>=448 (fused path only): w2 [E][NH][NM] fp32 -> w2t [E][NM][NH] bf16
// transpose, 2 64x64 tiles per 512-thread block -- memory-bound work that
// hides under gemm1 compute, eliminating the serial convert_wT launch.
__global__ __launch_bounds__(512, 2) void gemm1p_kernel(
        const unsigned short* __restrict__ xb, const unsigned short* __restrict__ wcat,
        unsigned short* __restrict__ hid,
        const float* __restrict__ w2, unsigned short* __restrict__ w2t) {
    const int tid = threadIdx.x;
    const int e = blockIdx.y;
    const int d = blockIdx.x;

    // 3 buf x (A 16 frags + B 16 frags) x 512 shorts = 96 KiB (gemm path)
    __shared__ __align__(16) unsigned short lds[3 * 16384];

    if (d >= 448) {
        // -------- fused w2 transpose: tile = 64x64, 2 tiles/block --------
        const int t = tid & 255;
        const int tile = (d - 448) * 2 + (tid >> 8);   // 0..3583
        const int tr = tile >> 5, tc = tile & 31;      // tiles_c = NM/64 = 32
        const float* ip = w2 + (size_t)e * NH * NM + (size_t)(tr * 64) * NM + tc * 64;
        unsigned short* op = w2t + (size_t)e * NM * NH + (size_t)(tc * 64) * NH + tr * 64;
        unsigned short (*tl)[68] = (unsigned short (*)[68])(lds + (tid >> 8) * 4352);

        const int rr = t >> 4, c4 = (t & 15) * 4;
#pragma unroll
        for (int q = 0; q < 4; ++q) {
            const int r = q * 16 + rr;
            f32x4 v = *(const f32x4*)(ip + (size_t)r * NM + c4);
            *(u16x4*)&tl[r][c4] = (u16x4){f2bf(v[0]), f2bf(v[1]), f2bf(v[2]), f2bf(v[3])};
        }
        __syncthreads();
#pragma unroll
        for (int q = 0; q < 4; ++q) {
            const int oc = q * 16 + rr;
            u16x4 v = (u16x4){tl[c4][oc], tl[c4 + 1][oc], tl[c4 + 2][oc], tl[c4 + 3][oc]};
            *(u16x4*)(op + (size_t)oc * NH + c4) = v;
        }
        return;
    }

    // ------------------------------ gemm1 path ------------------------------
    const int lane = tid & 63, wv = tid >> 6;          // 8 waves
    const int wr = wv >> 2, wc = wv & 3;               // 2M x 4N
    const int l = (d & 7) * 56 + (d >> 3);             // XCD-contiguous (448%8==0)
    const int ct = l >> 3, tt = l & 7;                 // ctile 0..55, ttile 0..7

    const unsigned short* ag = xb   + (size_t)(e * NT + tt * 256) * NM;
    const unsigned short* bg = wcat + (size_t)e * (2 * NH) * NM + (size_t)(ct * 256) * NM;
    unsigned short* hg = hid + (size_t)(e * NT + tt * 256) * NH + ct * 128;

    const int frow = lane & 15;            // staging src row within frag
    const int fks  = (lane >> 4) * 8;      // k offset within 32
    const int la   = lane * 8;             // frag-major read: lane*16B
    const int lr   = lane & 15, lq = lane >> 4;

    f32x4 acc[8][4];
#pragma unroll
    for (int m = 0; m < 8; ++m)
#pragma unroll
        for (int n = 0; n < 4; ++n) acc[m][n] = (f32x4){0.f, 0.f, 0.f, 0.f};

    auto stageA = [&](int t, int buf) {
        unsigned short* dst = lds + buf * 16384 + wv * 512;
        const unsigned short* src = ag + (size_t)(wv * 16 + frow) * NM + t * 32 + fks;
        gld16(src, dst);
        gld16(src + (size_t)128 * NM, dst + 8 * 512);
    };
    auto stageB = [&](int t, int buf) {
        unsigned short* dst = lds + buf * 16384 + 8192 + wv * 512;
        const unsigned short* src = bg + (size_t)(wv * 16 + frow) * NM + t * 32 + fks;
        gld16(src, dst);
        gld16(src + (size_t)128 * NM, dst + 8 * 512);
    };

    auto body = [&](int t, int buf, bool st2, int nbuf) {
        const unsigned short* bA = lds + buf * 16384;
        const unsigned short* bB = bA + 8192;
        bf16x8 af[4], bf[4];
        BAR();                             // publish tile t (each wave WAITV'd own loads)
#pragma unroll
        for (int m = 0; m < 4; ++m)
            af[m] = *(const bf16x8*)(bA + (wr * 8 + m) * 512 + la);
#pragma unroll
        for (int n = 0; n < 4; ++n)
            bf[n] = *(const bf16x8*)(bB + (wc * 4 + n) * 512 + la);
        __builtin_amdgcn_s_setprio(1);
#pragma unroll
        for (int m = 0; m < 4; ++m)
#pragma unroll
            for (int n = 0; n < 4; ++n)
                acc[m][n] = __builtin_amdgcn_mfma_f32_16x16x32_bf16(af[m], bf[n], acc[m][n], 0, 0, 0);
        __builtin_amdgcn_s_setprio(0);
        if (st2) stageB(t + 2, nbuf);
#pragma unroll
        for (int m = 0; m < 4; ++m)
            af[m] = *(const bf16x8*)(bA + (wr * 8 + 4 + m) * 512 + la);
        __builtin_amdgcn_s_setprio(1);
#pragma unroll
        for (int m = 0; m < 4; ++m)
#pragma unroll
            for (int n = 0; n < 4; ++n)
                acc[4 + m][n] = __builtin_amdgcn_mfma_f32_16x16x32_bf16(af[m], bf[n], acc[4 + m][n], 0, 0, 0);
        __builtin_amdgcn_s_setprio(0);
        BAR();                             // all reads of buf done before restage
    };

    const int NKT = NM / 32;               // 64
    stageA(0, 0); stageB(0, 0);
    stageA(1, 1); stageB(1, 1);

    int buf = 0, nbuf = 2;
    for (int t = 0; t < NKT - 2; ++t) {
        stageA(t + 2, nbuf);
        WAITV(6);                          // own A(t),B(t) landed; 6 newer in flight
        body(t, buf, true, nbuf);
        buf = (buf == 2) ? 0 : buf + 1;
        nbuf = (nbuf == 2) ? 0 : nbuf + 1;
    }
    WAITV(4);                              // A,B(NKT-2) landed
    body(NKT - 2, buf, false, 0);
    buf = (buf == 2) ? 0 : buf + 1;
    WAITV(0);
    body(NKT - 1, buf, false, 0);

    // epilogue: N-frags alternate gate(even)/up(odd) with identical lane map
#pragma unroll
    for (int mf = 0; mf < 8; ++mf)
#pragma unroll
        for (int p = 0; p < 2; ++p)
#pragma unroll
            for (int i = 0; i < 4; ++i) {
                const float g = acc[mf][2 * p][i];
                const float u = acc[mf][2 * p + 1][i];
                const float s = g / (1.f + __expf(-g));
                const int r = wr * 128 + mf * 16 + lq * 4 + i;
                const int h = wc * 32 + p * 16 + lr;
                hg[(size_t)r * NH + h] = f2bf(s * u);
            }
}

// ============ GEMM2 (R8 structure): out = hid * w2T^T, fp32 out ============
__global__ __launch_bounds__(512, 2) void gemm2p_kernel(
        const unsigned short* __restrict__ hid, const unsigned short* __restrict__ w2t,
        float* __restrict__ out) {
    const int tid = threadIdx.x;
    const int lane = tid & 63, wv = tid >> 6;
    const int wr = wv >> 2, wc = wv & 3;
    const int e = blockIdx.y;
    const int d = blockIdx.x;                          // 0..63
    const int l = (d & 7) * 8 + (d >> 3);
    const int mt = l >> 3, tt = l & 7;                 // mtile 0..7, ttile 0..7

    const unsigned short* ag = hid + (size_t)(e * NT + tt * 256) * NH;
    const unsigned short* bg = w2t + (size_t)e * NM * NH + (size_t)(mt * 256) * NH;
    float* og = out + (size_t)(e * NT + tt * 256) * NM + mt * 256;

    __shared__ __align__(16) unsigned short lds[3 * 16384];

    const int frow = lane & 15;
    const int fks  = (lane >> 4) * 8;
    const int la   = lane * 8;
    const int lr   = lane & 15, lq = lane >> 4;

    f32x4 acc[8][4];
#pragma unroll
    for (int m = 0; m < 8; ++m)
#pragma unroll
        for (int n = 0; n < 4; ++n) acc[m][n] = (f32x4){0.f, 0.f, 0.f, 0.f};

    auto stageA = [&](int t, int buf) {
        unsigned short* dst = lds + buf * 16384 + wv * 512;
        const unsigned short* src = ag + (size_t)(wv * 16 + frow) * NH + t * 32 + fks;
        gld16(src, dst);
        gld16(src + (size_t)128 * NH, dst + 8 * 512);
    };
    auto stageB = [&](int t, int buf) {
        unsigned short* dst = lds + buf * 16384 + 8192 + wv * 512;
        const unsigned short* src = bg + (size_t)(wv * 16 + frow) * NH + t * 32 + fks;
        gld16(src, dst);
        gld16(src + (size_t)128 * NH, dst + 8 * 512);
    };

    auto body = [&](int t, int buf, bool st2, int nbuf) {
        const unsigned short* bA = lds + buf * 16384;
        const unsigned short* bB = bA + 8192;
        bf16x8 af[4], bf[4];
        BAR();
#pragma unroll
        for (int m = 0; m < 4; ++m)
            af[m] = *(const bf16x8*)(bA + (wr * 8 + m) * 512 + la);
#pragma unroll
        for (int n = 0; n < 4; ++n)
            bf[n] = *(const bf16x8*)(bB + (wc * 4 + n) * 512 + la);
        __builtin_amdgcn_s_setprio(1);
#pragma unroll
        for (int m = 0; m < 4; ++m)
#pragma unroll
            for (int n = 0; n < 4; ++n)
                acc[m][n] = __builtin_amdgcn_mfma_f32_16x16x32_bf16(af[m], bf[n], acc[m][n], 0, 0, 0);
        __builtin_amdgcn_s_setprio(0);
        if (st2) stageB(t + 2, nbuf);
#pragma unroll
        for (int m = 0; m < 4; ++m)
            af[m] = *(const bf16x8*)(bA + (wr * 8 + 4 + m) * 512 + la);
        __builtin_amdgcn_s_setprio(1);
#pragma unroll
        for (int m = 0; m < 4; ++m)
#pragma unroll
            for (int n = 0; n < 4; ++n)
                acc[4 + m][n] = __builtin_amdgcn_mfma_f32_16x16x32_bf16(af[m], bf[n], acc[4 + m][n], 0, 0, 0);
        __builtin_amdgcn_s_setprio(0);
        BAR();
    };

    const int NKT = NH / 32;               // 224
    stageA(0, 0); stageB(0, 0);
    stageA(1, 1); stageB(1, 1);

    int buf = 0, nbuf = 2;
    for (int t = 0; t < NKT - 2; ++t) {
        stageA(t + 2, nbuf);
        WAITV(6);
        body(t, buf, true, nbuf);
        buf = (buf == 2) ? 0 : buf + 1;
        nbuf = (nbuf == 2) ? 0 : nbuf + 1;
    }
    WAITV(4);
    body(NKT - 2, buf, false, 0);
    buf = (buf == 2) ? 0 : buf + 1;
    WAITV(0);
    body(NKT - 1, buf, false, 0);

#pragma unroll
    for (int mf = 0; mf < 8; ++mf)
#pragma unroll
        for (int n = 0; n < 4; ++n)
#pragma unroll
            for (int i = 0; i < 4; ++i) {
                const int r = wr * 128 + mf * 16 + lq * 4 + i;
                const int c = wc * 64 + n * 16 + lr;
                og[(size_t)r * NM + c] = acc[mf][n][i];
            }
}

// ===================== fallback (round-1, fused-convert) =====================
#define ROWB 80
#define TILEB (128 * ROWB)

__global__ __launch_bounds__(256, 2) void gemm1_fb_kernel(
        const float* __restrict__ x, const float* __restrict__ w1,
        const float* __restrict__ w3, unsigned short* __restrict__ hid) {
    const int tid = threadIdx.x;
    const int e = blockIdx.y;
    const int d = blockIdx.x;
    const int l = (d & 7) * 112 + (d >> 3);
    const int hn = l >> 4, tm = l & 15;

    const float* xg  = x  + (size_t)(e * NT + tm * 128) * NM;
    const float* w1g = w1 + (size_t)e * NM * NH + hn * 128;
    const float* w3g = w3 + (size_t)e * NM * NH + hn * 128;
    unsigned short* hg = hid + (size_t)(e * NT + tm * 128) * NH + hn * 128;

    __shared__ __align__(16) unsigned char lds[2 * 3 * TILEB];

    const int a_r = tid >> 3, a_c4 = tid & 7;
    const int w_kq = (tid >> 2) & 7;
    const int w_cg = ((tid >> 5) << 2) | (tid & 3);

    const int lane = tid & 63;
    const int wv = tid >> 6;
    const int r0w = (wv >> 1) * 64, c0w = (wv & 1) * 64;
    const int lr = lane & 15, lq = lane >> 4;

    f32x4 accg[4][4], accu[4][4];
#pragma unroll
    for (int m = 0; m < 4; ++m)
#pragma unroll
        for (int n = 0; n < 4; ++n) {
            accg[m][n] = (f32x4){0.f, 0.f, 0.f, 0.f};
            accu[m][n] = (f32x4){0.f, 0.f, 0.f, 0.f};
        }

    f32x4 la0, la1, la2, la3;
    f32x4 l10, l11, l12, l13, l30, l31, l32, l33;

    auto stage_load = [&](int ks) {
        const int k0 = ks * 32;
        const float* pa = xg + (size_t)a_r * NM + k0 + a_c4 * 4;
        la0 = *(const f32x4*)(pa);
        la1 = *(const f32x4*)(pa + 32 * NM);
        la2 = *(const f32x4*)(pa + 64 * NM);
        la3 = *(const f32x4*)(pa + 96 * NM);
        const float* p1 = w1g + (size_t)(k0 + w_kq * 4) * NH + w_cg * 4;
        l10 = *(const f32x4*)(p1);
        l11 = *(const f32x4*)(p1 + NH);
        l12 = *(const f32x4*)(p1 + 2 * NH);
        l13 = *(const f32x4*)(p1 + 3 * NH);
        const float* p3 = w3g + (size_t)(k0 + w_kq * 4) * NH + w_cg * 4;
        l30 = *(const f32x4*)(p3);
        l31 = *(const f32x4*)(p3 + NH);
        l32 = *(const f32x4*)(p3 + 2 * NH);
        l33 = *(const f32x4*)(p3 + 3 * NH);
    };

    auto stage_write = [&](int buf) {
        unsigned char* base = lds + buf * (3 * TILEB);
        unsigned char* pa = base + a_r * ROWB + a_c4 * 8;
        *(u16x4*)(pa)             = (u16x4){f2bf(la0[0]), f2bf(la0[1]), f2bf(la0[2]), f2bf(la0[3])};
        *(u16x4*)(pa + 32 * ROWB) = (u16x4){f2bf(la1[0]), f2bf(la1[1]), f2bf(la1[2]), f2bf(la1[3])};
        *(u16x4*)(pa + 64 * ROWB) = (u16x4){f2bf(la2[0]), f2bf(la2[1]), f2bf(la2[2]), f2bf(la2[3])};
        *(u16x4*)(pa + 96 * ROWB) = (u16x4){f2bf(la3[0]), f2bf(la3[1]), f2bf(la3[2]), f2bf(la3[3])};
        unsigned char* pw1 = base + TILEB + w_kq * 8;
#pragma unroll
        for (int j = 0; j < 4; ++j) {
            const int c = w_cg * 4 + j;
            *(u16x4*)(pw1 + c * ROWB) =
                (u16x4){f2bf(l10[j]), f2bf(l11[j]), f2bf(l12[j]), f2bf(l13[j])};
        }
        unsigned char* pw3 = base + 2 * TILEB + w_kq * 8;
#pragma unroll
        for (int j = 0; j < 4; ++j) {
            const int c = w_cg * 4 + j;
            *(u16x4*)(pw3 + c * ROWB) =
                (u16x4){f2bf(l30[j]), f2bf(l31[j]), f2bf(l32[j]), f2bf(l33[j])};
        }
    };

    auto compute = [&](int buf) {
        const unsigned char* base = lds + buf * (3 * TILEB);
        bf16x8 af[4], b1f[4], b3f[4];
#pragma unroll
        for (int m = 0; m < 4; ++m)
            af[m] = *(const bf16x8*)(base + (r0w + m * 16 + lr) * ROWB + lq * 16);
#pragma unroll
        for (int n = 0; n < 4; ++n) {
            b1f[n] = *(const bf16x8*)(base + TILEB + (c0w + n * 16 + lr) * ROWB + lq * 16);
            b3f[n] = *(const bf16x8*)(base + 2 * TILEB + (c0w + n * 16 + lr) * ROWB + lq * 16);
        }
#pragma unroll
        for (int m = 0; m < 4; ++m)
#pragma unroll
            for (int n = 0; n < 4; ++n) {
                accg[m][n] = __builtin_amdgcn_mfma_f32_16x16x32_bf16(af[m], b1f[n], accg[m][n], 0, 0, 0);
                accu[m][n] = __builtin_amdgcn_mfma_f32_16x16x32_bf16(af[m], b3f[n], accu[m][n], 0, 0, 0);
            }
    };

    stage_load(0);
    stage_write(0);
    __syncthreads();
    int cur = 0;
    const int NK = NM / 32;
    for (int ks = 0; ks < NK; ++ks) {
        const bool more = (ks + 1 < NK);
        if (more) stage_load(ks + 1);
        compute(cur);
        if (more) {
            stage_write(cur ^ 1);
            __syncthreads();
        }
        cur ^= 1;
    }

#pragma unroll
    for (int m = 0; m < 4; ++m)
#pragma unroll
        for (int n = 0; n < 4; ++n)
#pragma unroll
            for (int i = 0; i < 4; ++i) {
                const float g = accg[m][n][i];
                const float u = accu[m][n][i];
                const float s = g / (1.f + __expf(-g));
                const int r = r0w + m * 16 + lq * 4 + i;
                const int c = c0w + n * 16 + lr;
                hg[(size_t)r * NH + c] = f2bf(s * u);
            }
}

__global__ __launch_bounds__(256, 2) void gemm2_fb_kernel(
        const unsigned short* __restrict__ hid, const float* __restrict__ w2,
        float* __restrict__ out) {
    const int tid = threadIdx.x;
    const int e = blockIdx.y;
    const int d = blockIdx.x;
    const int l = (d & 7) * 32 + (d >> 3);
    const int mn = l >> 4, tm = l & 15;

    const unsigned short* ag = hid + (size_t)(e * NT + tm * 128) * NH;
    const float* wg = w2 + (size_t)e * NH * NM + mn * 128;
    float* og = out + (size_t)(e * NT + tm * 128) * NM + mn * 128;

    __shared__ __align__(16) unsigned char lds[2 * 2 * TILEB];

    const int a_row = tid >> 2, a_ch = tid & 3;
    const int w_kq = (tid >> 2) & 7;
    const int w_cg = ((tid >> 5) << 2) | (tid & 3);

    const int lane = tid & 63;
    const int wv = tid >> 6;
    const int r0w = (wv >> 1) * 64, c0w = (wv & 1) * 64;
    const int lr = lane & 15, lq = lane >> 4;

    f32x4 acc[4][4];
#pragma unroll
    for (int m = 0; m < 4; ++m)
#pragma unroll
        for (int n = 0; n < 4; ++n) acc[m][n] = (f32x4){0.f, 0.f, 0.f, 0.f};

    u32x4 lau0, lau1;
    f32x4 lw0, lw1, lw2, lw3;

    auto stage_load = [&](int ks) {
        const int k0 = ks * 32;
        lau0 = *(const u32x4*)(ag + (size_t)a_row * NH + k0 + a_ch * 8);
        lau1 = *(const u32x4*)(ag + (size_t)(a_row + 64) * NH + k0 + a_ch * 8);
        const float* p = wg + (size_t)(k0 + w_kq * 4) * NM + w_cg * 4;
        lw0 = *(const f32x4*)(p);
        lw1 = *(const f32x4*)(p + NM);
        lw2 = *(const f32x4*)(p + 2 * NM);
        lw3 = *(const f32x4*)(p + 3 * NM);
    };

    auto stage_write = [&](int buf) {
        unsigned char* base = lds + buf * (2 * TILEB);
        *(u32x4*)(base + a_row * ROWB + a_ch * 16) = lau0;
        *(u32x4*)(base + (a_row + 64) * ROWB + a_ch * 16) = lau1;
        unsigned char* pw = base + TILEB + w_kq * 8;
#pragma unroll
        for (int j = 0; j < 4; ++j) {
            const int c = w_cg * 4 + j;
            *(u16x4*)(pw + c * ROWB) =
                (u16x4){f2bf(lw0[j]), f2bf(lw1[j]), f2bf(lw2[j]), f2bf(lw3[j])};
        }
    };

    auto compute = [&](int buf) {
        const unsigned char* base = lds + buf * (2 * TILEB);
        bf16x8 af[4], bf[4];
#pragma unroll
        for (int m = 0; m < 4; ++m)
            af[m] = *(const bf16x8*)(base + (r0w + m * 16 + lr) * ROWB + lq * 16);
#pragma unroll
        for (int n = 0; n < 4; ++n)
            bf[n] = *(const bf16x8*)(base + TILEB + (c0w + n * 16 + lr) * ROWB + lq * 16);
#pragma unroll
        for (int m = 0; m < 4; ++m)
#pragma unroll
            for (int n = 0; n < 4; ++n)
                acc[m][n] = __builtin_amdgcn_mfma_f32_16x16x32_bf16(af[m], bf[n], acc[m][n], 0, 0, 0);
    };

    stage_load(0);
    stage_write(0);
    __syncthreads();
    int cur = 0;
    const int NK = NH / 32;
    for (int ks = 0; ks < NK; ++ks) {
        const bool more = (ks + 1 < NK);
        if (more) stage_load(ks + 1);
        compute(cur);
        if (more) {
            stage_write(cur ^ 1);
            __syncthreads();
        }
        cur ^= 1;
    }

#pragma unroll
    for (int m = 0; m < 4; ++m)
#pragma unroll
        for (int n = 0; n < 4; ++n)
#pragma unroll
            for (int i = 0; i < 4; ++i) {
                const int r = r0w + m * 16 + lq * 4 + i;
                const int c = c0w + n * 16 + lr;
                og[(size_t)r * NM + c] = acc[m][n][i];
            }
}

// ================================ launcher ================================

extern "C" void kernel_launch(void* const* d_in, const int* in_sizes, int n_in,
                              void* d_out, int out_size, void* d_ws, size_t ws_size,
                              hipStream_t stream) {
    const float* x  = (const float*)d_in[0];
    const float* w1 = (const float*)d_in[1];
    const float* w2 = (const float*)d_in[2];
    const float* w3 = (const float*)d_in[3];
    float* out = (float*)d_out;

    const size_t XB_SZ   = (size_t)NE * NT * NM * 2;        //  64 MiB
    const size_t WCAT_SZ = (size_t)NE * 2 * NH * NM * 2;    // 448 MiB
    const size_t HID_SZ  = (size_t)NE * NT * NH * 2;        // 224 MiB
    const size_t W2T_SZ  = (size_t)NE * NM * NH * 2;        // 224 MiB
    const size_t NEED_FULL = XB_SZ + WCAT_SZ + HID_SZ + W2T_SZ;  // 960 MiB
    const size_t NEED_STD  = XB_SZ + WCAT_SZ + HID_SZ;           // 736 MiB

    unsigned char* ws = (unsigned char*)d_ws;

    if (ws_size >= NEED_FULL) {
        // fused path: w2t disjoint -> w2-transpose rides inside gemm1p launch
        unsigned short* xbp  = (unsigned short*)(ws);
        unsigned short* wcat = (unsigned short*)(ws + XB_SZ);
        unsigned short* hidb = (unsigned short*)(ws + XB_SZ + WCAT_SZ);
        unsigned short* w2t  = (unsigned short*)(ws + XB_SZ + WCAT_SZ + HID_SZ);

        convert_x_kernel<<<dim3((NE * NT * NM) / 1024), 256, 0, stream>>>(x, xbp);
        convert_w13_kernel<<<dim3((NM / 64) * (NH / 64), NE), 256, 0, stream>>>(w1, w3, wcat);
        gemm1p_kernel<<<dim3(448 + 1792, NE), 512, 0, stream>>>(xbp, wcat, hidb, w2, w2t);
        gemm2p_kernel<<<dim3(64, NE), 512, 0, stream>>>(hidb, w2t, out);
    } else if (ws_size >= NEED_STD) {
        // std path (round-8 measured): separate w2 transpose after gemm1
        unsigned short* xbp  = (unsigned short*)(ws);
        unsigned short* wcat = (unsigned short*)(ws + XB_SZ);
        unsigned short* hidb = (unsigned short*)(ws + XB_SZ + WCAT_SZ);
        unsigned short* w2t  = (unsigned short*)(ws);   // reuses xb/wcat after gemm1

        convert_x_kernel<<<dim3((NE * NT * NM) / 1024), 256, 0, stream>>>(x, xbp);
        convert_w13_kernel<<<dim3((NM / 64) * (NH / 64), NE), 256, 0, stream>>>(w1, w3, wcat);
        gemm1p_kernel<<<dim3(448, NE), 512, 0, stream>>>(xbp, wcat, hidb, w2, w2t);
        convert_wT_kernel<<<dim3((NH / 64) * (NM / 64), NE), 256, 0, stream>>>(w2, w2t, NH, NM);
        gemm2p_kernel<<<dim3(64, NE), 512, 0, stream>>>(hidb, w2t, out);
    } else {
        unsigned short* hid = (unsigned short*)d_ws;
        gemm1_fb_kernel<<<dim3(896, NE), 256, 0, stream>>>(x, w1, w3, hid);
        gemm2_fb_kernel<<<dim3(256, NE), 256, 0, stream>>>(hid, w2, out);
    }
}

// Round 14
// 1658.104 us; speedup vs baseline: 1.7463x; 1.1651x over previous
//
#include <hip/hip_runtime.h>

typedef __attribute__((ext_vector_type(8))) short bf16x8;
typedef __attribute__((ext_vector_type(4))) float f32x4;
typedef __attribute__((ext_vector_type(4))) unsigned int u32x4;
typedef __attribute__((ext_vector_type(4))) unsigned short u16x4;

#define NE 8
#define NT 2048   // tokens per expert (B*C)
#define NM 2048
#define NH 7168

// Raw barrier (no implicit vmcnt(0) drain) + counted vmcnt waits.
#define BAR() asm volatile("s_barrier" ::: "memory")
#define WAITV(N) asm volatile("s_waitcnt vmcnt(" #N ")" ::: "memory")

__device__ __forceinline__ unsigned short f2bf(float f) {
    unsigned int u = __float_as_uint(f);
    return (unsigned short)((u + 0x7fffu + ((u >> 16) & 1u)) >> 16);  // RNE
}

__device__ __forceinline__ void gld16(const void* g, void* l) {
    __builtin_amdgcn_global_load_lds(
        (const __attribute__((address_space(1))) void*)g,
        (__attribute__((address_space(3))) void*)l, 16, 0, 0);
}

// ===================== tiled-layout conversion kernels =====================
// Frag-major global layouts: [tile][k-step t][frag f(16)][lane l(64) x 16B].
// Slot (f,l) of an A-type tile tt: token = tt*256+f*16+(l&15), k = t*32+(l>>4)*8.
// Staging then reads 1KB CONTIGUOUS per gld16 (1 segment vs 16 -- the r13 fix).

// x fp32 -> xb_t tiled bf16. One slot (8 elems) per thread; writes coalesced.
__global__ __launch_bounds__(256) void convert_x_kernel(
        const float* __restrict__ in, unsigned short* __restrict__ out) {
    const int s = blockIdx.x * 256 + threadIdx.x;          // slot id
    const int l = s & 63;
    const int f = (s >> 6) & 15;
    const int t = (s >> 10) & 63;
    const int tt = (s >> 16) & 7;
    const int e = s >> 19;
    const int tok = tt * 256 + f * 16 + (l & 15);
    const int k = t * 32 + (l >> 4) * 8;
    const float* p = in + (size_t)(e * NT + tok) * NM + k;
    f32x4 a = *(const f32x4*)p;
    f32x4 b = *(const f32x4*)(p + 4);
    unsigned short* o = out + (size_t)s * 8;
    *(u16x4*)o       = (u16x4){f2bf(a[0]), f2bf(a[1]), f2bf(a[2]), f2bf(a[3])};
    *(u16x4*)(o + 4) = (u16x4){f2bf(b[0]), f2bf(b[1]), f2bf(b[2]), f2bf(b[3])};
}

// w1,w3 [E][M][H] fp32 -> wcat_t tiled bf16. B-tile ct covers h in
// [ct*128,+128): INTERLEAVED frags (gate even / up odd, matching the gemm1
// epilogue pairing): fh = hblock*2 + which, hblock = (gh>>4)&7.
// frag fh: h = ct*128 + (fh>>1)*16 + (l&15); k = t*32 + (l>>4)*8.
__global__ __launch_bounds__(256) void convert_w13_kernel(
        const float* __restrict__ w1, const float* __restrict__ w3,
        unsigned short* __restrict__ wcat) {
    const int t = threadIdx.x;
    const int e = blockIdx.y;
    const int tiles_c = NH >> 6;              // 112 h-tiles
    const int tr = blockIdx.x / tiles_c;      // k-tile (NM/64 = 32)
    const int tc = blockIdx.x % tiles_c;      // h-tile

    __shared__ unsigned short tl[64][68];
    const int rr = t >> 4, c4 = (t & 15) * 4;

#pragma unroll
    for (int pass = 0; pass < 2; ++pass) {
        const float* ip = (pass ? w3 : w1) + (size_t)e * NM * NH + (size_t)(tr * 64) * NH + tc * 64;
        if (pass) __syncthreads();
#pragma unroll
        for (int q = 0; q < 4; ++q) {
            const int r = q * 16 + rr;        // k within tile
            f32x4 v = *(const f32x4*)(ip + (size_t)r * NH + c4);
            *(u16x4*)&tl[r][c4] = (u16x4){f2bf(v[0]), f2bf(v[1]), f2bf(v[2]), f2bf(v[3])};
        }
        __syncthreads();
        const int gk = tr * 64 + c4;
        const int tk = gk >> 5, krun = (gk >> 3) & 3, j = gk & 7;   // j in {0,4}
#pragma unroll
        for (int q = 0; q < 4; ++q) {
            const int oc = q * 16 + rr;       // h within tile
            const int gh = tc * 64 + oc;
            const int ct = gh >> 7;
            const int fh = (((gh >> 4) & 7) << 1) + pass;   // INTERLEAVE (bug fix)
            const int lp = gh & 15;
            u16x4 v = (u16x4){tl[c4][oc], tl[c4 + 1][oc], tl[c4 + 2][oc], tl[c4 + 3][oc]};
            unsigned short* dst = wcat + ((((size_t)(e * 56 + ct) * 64 + tk) * 16 + fh) << 9)
                                  + (lp + (krun << 4)) * 8 + j;
            *(u16x4*)dst = v;
        }
    }
}

// w2 [E][NH][NM] fp32 -> w2t_t tiled bf16 (B of gemm2): frag f: m = mt*256 +
// f*16 + (l&15), h(k) = t*32 + (l>>4)*8. Shared by standalone + fused paths.
__device__ __forceinline__ void w2_transpose_tile(
        const float* __restrict__ w2, unsigned short* __restrict__ w2t,
        int e, int tile, int t, unsigned short (*tl)[68]) {
    const int tr = tile >> 5;                 // h-tile (NH/64 = 112)
    const int tc = tile & 31;                 // m-tile (NM/64 = 32)
    const float* ip = w2 + (size_t)e * NH * NM + (size_t)(tr * 64) * NM + tc * 64;
    const int rr = t >> 4, c4 = (t & 15) * 4;
#pragma unroll
    for (int q = 0; q < 4; ++q) {
        const int r = q * 16 + rr;            // h within tile
        f32x4 v = *(const f32x4*)(ip + (size_t)r * NM + c4);
        *(u16x4*)&tl[r][c4] = (u16x4){f2bf(v[0]), f2bf(v[1]), f2bf(v[2]), f2bf(v[3])};
    }
    __syncthreads();
    const int gh = tr * 64 + c4;
    const int tk = gh >> 5, krun = (gh >> 3) & 3, j = gh & 7;
#pragma unroll
    for (int q = 0; q < 4; ++q) {
        const int oc = q * 16 + rr;           // m within tile
        const int gm = tc * 64 + oc;
        const int mt = gm >> 8, fm = (gm >> 4) & 15, lp = gm & 15;
        u16x4 v = (u16x4){tl[c4][oc], tl[c4 + 1][oc], tl[c4 + 2][oc], tl[c4 + 3][oc]};
        unsigned short* dst = w2t + ((((size_t)(e * 8 + mt) * 224 + tk) * 16 + fm) << 9)
                              + (lp + (krun << 4)) * 8 + j;
        *(u16x4*)dst = v;
    }
}

__global__ __launch_bounds__(256) void convert_w2t_kernel(
        const float* __restrict__ w2, unsigned short* __restrict__ w2t) {
    __shared__ unsigned short tl[64][68];
    w2_transpose_tile(w2, w2t, blockIdx.y, blockIdx.x, threadIdx.x, tl);
}

// ====== GEMM1 (R8 pipeline + tiled layouts) + optional fused w2-transpose ======
// Blocks d<448: gemm1. Staging reads 1KB contiguous per gld16.
// Blocks d>=448 (fused path): w2 transpose, 2 tiles per 512-thread block.
__global__ __launch_bounds__(512, 2) void gemm1p_kernel(
        const unsigned short* __restrict__ xb, const unsigned short* __restrict__ wcat,
        unsigned short* __restrict__ hid,
        const float* __restrict__ w2, unsigned short* __restrict__ w2t) {
    const int tid = threadIdx.x;
    const int e = blockIdx.y;
    const int d = blockIdx.x;

    // gemm path: 3 buf x (A 16 frags + B 16 frags) x 512 shorts = 96 KiB
    __shared__ __align__(16) unsigned short lds[3 * 16384];

    if (d >= 448) {
        const int tile = (d - 448) * 2 + (tid >> 8);   // 0..3583
        unsigned short (*tl)[68] = (unsigned short (*)[68])(lds + (tid >> 8) * 4352);
        w2_transpose_tile(w2, w2t, e, tile, tid & 255, tl);
        return;
    }

    const int lane = tid & 63, wv = tid >> 6;          // 8 waves
    const int wr = wv >> 2, wc = wv & 3;               // 2M x 4N
    const int l = (d & 7) * 56 + (d >> 3);             // XCD-contiguous
    const int ct = l >> 3, tt = l & 7;                 // ctile 0..55, ttile 0..7

    const unsigned short* ag = xb   + (size_t)(e * 8 + tt) * 64 * 8192;
    const unsigned short* bg = wcat + (size_t)(e * 56 + ct) * 64 * 8192;
    unsigned short* hb = hid + (size_t)(e * 8 + tt) * 224 * 8192;

    const int la = lane * 8;               // frag-major: lane*16B
    const int lr = lane & 15, lq = lane >> 4;

    f32x4 acc[8][4];
#pragma unroll
    for (int m = 0; m < 8; ++m)
#pragma unroll
        for (int n = 0; n < 4; ++n) acc[m][n] = (f32x4){0.f, 0.f, 0.f, 0.f};

    // wave wv stages frags wv and wv+8; src contiguous 1KB per gld16
    auto stageA = [&](int t, int buf) {
        unsigned short* dst = lds + buf * 16384 + wv * 512;
        const unsigned short* src = ag + (((size_t)t * 16 + wv) << 9) + la;
        gld16(src, dst);
        gld16(src + 8 * 512, dst + 8 * 512);
    };
    auto stageB = [&](int t, int buf) {
        unsigned short* dst = lds + buf * 16384 + 8192 + wv * 512;
        const unsigned short* src = bg + (((size_t)t * 16 + wv) << 9) + la;
        gld16(src, dst);
        gld16(src + 8 * 512, dst + 8 * 512);
    };

    auto body = [&](int t, int buf, bool st2, int nbuf) {
        const unsigned short* bA = lds + buf * 16384;
        const unsigned short* bB = bA + 8192;
        bf16x8 af[4], bf[4];
        BAR();                             // publish tile t
#pragma unroll
        for (int m = 0; m < 4; ++m)
            af[m] = *(const bf16x8*)(bA + (wr * 8 + m) * 512 + la);
#pragma unroll
        for (int n = 0; n < 4; ++n)
            bf[n] = *(const bf16x8*)(bB + (wc * 4 + n) * 512 + la);
        __builtin_amdgcn_s_setprio(1);
#pragma unroll
        for (int m = 0; m < 4; ++m)
#pragma unroll
            for (int n = 0; n < 4; ++n)
                acc[m][n] = __builtin_amdgcn_mfma_f32_16x16x32_bf16(af[m], bf[n], acc[m][n], 0, 0, 0);
        __builtin_amdgcn_s_setprio(0);
        if (st2) stageB(t + 2, nbuf);
#pragma unroll
        for (int m = 0; m < 4; ++m)
            af[m] = *(const bf16x8*)(bA + (wr * 8 + 4 + m) * 512 + la);
        __builtin_amdgcn_s_setprio(1);
#pragma unroll
        for (int m = 0; m < 4; ++m)
#pragma unroll
            for (int n = 0; n < 4; ++n)
                acc[4 + m][n] = __builtin_amdgcn_mfma_f32_16x16x32_bf16(af[m], bf[n], acc[4 + m][n], 0, 0, 0);
        __builtin_amdgcn_s_setprio(0);
        BAR();                             // reads done before restage
    };

    const int NKT = NM / 32;               // 64
    stageA(0, 0); stageB(0, 0);
    stageA(1, 1); stageB(1, 1);

    int buf = 0, nbuf = 2;
    for (int t = 0; t < NKT - 2; ++t) {
        stageA(t + 2, nbuf);
        WAITV(6);                          // own A(t),B(t) landed; 6 newer flying
        body(t, buf, true, nbuf);
        buf = (buf == 2) ? 0 : buf + 1;
        nbuf = (nbuf == 2) ? 0 : nbuf + 1;
    }
    WAITV(4);
    body(NKT - 2, buf, false, 0);
    buf = (buf == 2) ? 0 : buf + 1;
    WAITV(0);
    body(NKT - 1, buf, false, 0);

    // epilogue: silu(gate)*up -> hid in gemm2's frag-major tiled layout.
    // token = tt*256 + wr*128 + mf*16 + lq*4+i ; gh = ct*128 + wc*32 + p*16 + lr
    // (B frag wc*4+n = h-block wc*2+(n>>1), which=n&1 under the interleave)
    // -> tk = ct*4+wc, f = wr*8+mf, lp = lq*4+i, krun = p*2+(lr>>3), j = lr&7
    {
        unsigned short* hb2 = hb + (((size_t)(ct * 4 + wc) * 16) << 9);
        const int jj = lr & 7;
#pragma unroll
        for (int mf = 0; mf < 8; ++mf)
#pragma unroll
            for (int p = 0; p < 2; ++p)
#pragma unroll
                for (int i = 0; i < 4; ++i) {
                    const float g = acc[mf][2 * p][i];
                    const float u = acc[mf][2 * p + 1][i];
                    const float s = g / (1.f + __expf(-g));
                    const int fidx = wr * 8 + mf;
                    const int lidx = (lq * 4 + i) + ((p * 2 + (lr >> 3)) << 4);
                    hb2[((size_t)fidx << 9) + lidx * 8 + jj] = f2bf(s * u);
                }
    }
}

// ============ GEMM2 (R8 pipeline + tiled layouts): out = hid * w2T^T ============
__global__ __launch_bounds__(512, 2) void gemm2p_kernel(
        const unsigned short* __restrict__ hid, const unsigned short* __restrict__ w2t,
        float* __restrict__ out) {
    const int tid = threadIdx.x;
    const int lane = tid & 63, wv = tid >> 6;
    const int wr = wv >> 2, wc = wv & 3;
    const int e = blockIdx.y;
    const int d = blockIdx.x;                          // 0..63
    const int l = (d & 7) * 8 + (d >> 3);
    const int mt = l >> 3, tt = l & 7;

    const unsigned short* ag = hid + (size_t)(e * 8 + tt) * 224 * 8192;
    const unsigned short* bg = w2t + (size_t)(e * 8 + mt) * 224 * 8192;
    float* og = out + (size_t)(e * NT + tt * 256) * NM + mt * 256;

    __shared__ __align__(16) unsigned short lds[3 * 16384];

    const int la = lane * 8;
    const int lr = lane & 15, lq = lane >> 4;

    f32x4 acc[8][4];
#pragma unroll
    for (int m = 0; m < 8; ++m)
#pragma unroll
        for (int n = 0; n < 4; ++n) acc[m][n] = (f32x4){0.f, 0.f, 0.f, 0.f};

    auto stageA = [&](int t, int buf) {
        unsigned short* dst = lds + buf * 16384 + wv * 512;
        const unsigned short* src = ag + (((size_t)t * 16 + wv) << 9) + la;
        gld16(src, dst);
        gld16(src + 8 * 512, dst + 8 * 512);
    };
    auto stageB = [&](int t, int buf) {
        unsigned short* dst = lds + buf * 16384 + 8192 + wv * 512;
        const unsigned short* src = bg + (((size_t)t * 16 + wv) << 9) + la;
        gld16(src, dst);
        gld16(src + 8 * 512, dst + 8 * 512);
    };

    auto body = [&](int t, int buf, bool st2, int nbuf) {
        const unsigned short* bA = lds + buf * 16384;
        const unsigned short* bB = bA + 8192;
        bf16x8 af[4], bf[4];
        BAR();
#pragma unroll
        for (int m = 0; m < 4; ++m)
            af[m] = *(const bf16x8*)(bA + (wr * 8 + m) * 512 + la);
#pragma unroll
        for (int n = 0; n < 4; ++n)
            bf[n] = *(const bf16x8*)(bB + (wc * 4 + n) * 512 + la);
        __builtin_amdgcn_s_setprio(1);
#pragma unroll
        for (int m = 0; m < 4; ++m)
#pragma unroll
            for (int n = 0; n < 4; ++n)
                acc[m][n] = __builtin_amdgcn_mfma_f32_16x16x32_bf16(af[m], bf[n], acc[m][n], 0, 0, 0);
        __builtin_amdgcn_s_setprio(0);
        if (st2) stageB(t + 2, nbuf);
#pragma unroll
        for (int m = 0; m < 4; ++m)
            af[m] = *(const bf16x8*)(bA + (wr * 8 + 4 + m) * 512 + la);
        __builtin_amdgcn_s_setprio(1);
#pragma unroll
        for (int m = 0; m < 4; ++m)
#pragma unroll
            for (int n = 0; n < 4; ++n)
                acc[4 + m][n] = __builtin_amdgcn_mfma_f32_16x16x32_bf16(af[m], bf[n], acc[4 + m][n], 0, 0, 0);
        __builtin_amdgcn_s_setprio(0);
        BAR();
    };

    const int NKT = NH / 32;               // 224
    stageA(0, 0); stageB(0, 0);
    stageA(1, 1); stageB(1, 1);

    int buf = 0, nbuf = 2;
    for (int t = 0; t < NKT - 2; ++t) {
        stageA(t + 2, nbuf);
        WAITV(6);
        body(t, buf, true, nbuf);
        buf = (buf == 2) ? 0 : buf + 1;
        nbuf = (nbuf == 2) ? 0 : nbuf + 1;
    }
    WAITV(4);
    body(NKT - 2, buf, false, 0);
    buf = (buf == 2) ? 0 : buf + 1;
    WAITV(0);
    body(NKT - 1, buf, false, 0);

#pragma unroll
    for (int mf = 0; mf < 8; ++mf)
#pragma unroll
        for (int n = 0; n < 4; ++n)
#pragma unroll
            for (int i = 0; i < 4; ++i) {
                const int r = wr * 128 + mf * 16 + lq * 4 + i;
                const int c = wc * 64 + n * 16 + lr;
                og[(size_t)r * NM + c] = acc[mf][n][i];
            }
}

// ===================== fallback (round-1, fused-convert) =====================
#define ROWB 80
#define TILEB (128 * ROWB)

__global__ __launch_bounds__(256, 2) void gemm1_fb_kernel(
        const float* __restrict__ x, const float* __restrict__ w1,
        const float* __restrict__ w3, unsigned short* __restrict__ hid) {
    const int tid = threadIdx.x;
    const int e = blockIdx.y;
    const int d = blockIdx.x;
    const int l = (d & 7) * 112 + (d >> 3);
    const int hn = l >> 4, tm = l & 15;

    const float* xg  = x  + (size_t)(e * NT + tm * 128) * NM;
    const float* w1g = w1 + (size_t)e * NM * NH + hn * 128;
    const float* w3g = w3 + (size_t)e * NM * NH + hn * 128;
    unsigned short* hg = hid + (size_t)(e * NT + tm * 128) * NH + hn * 128;

    __shared__ __align__(16) unsigned char lds[2 * 3 * TILEB];

    const int a_r = tid >> 3, a_c4 = tid & 7;
    const int w_kq = (tid >> 2) & 7;
    const int w_cg = ((tid >> 5) << 2) | (tid & 3);

    const int lane = tid & 63;
    const int wv = tid >> 6;
    const int r0w = (wv >> 1) * 64, c0w = (wv & 1) * 64;
    const int lr = lane & 15, lq = lane >> 4;

    f32x4 accg[4][4], accu[4][4];
#pragma unroll
    for (int m = 0; m < 4; ++m)
#pragma unroll
        for (int n = 0; n < 4; ++n) {
            accg[m][n] = (f32x4){0.f, 0.f, 0.f, 0.f};
            accu[m][n] = (f32x4){0.f, 0.f, 0.f, 0.f};
        }

    f32x4 la0, la1, la2, la3;
    f32x4 l10, l11, l12, l13, l30, l31, l32, l33;

    auto stage_load = [&](int ks) {
        const int k0 = ks * 32;
        const float* pa = xg + (size_t)a_r * NM + k0 + a_c4 * 4;
        la0 = *(const f32x4*)(pa);
        la1 = *(const f32x4*)(pa + 32 * NM);
        la2 = *(const f32x4*)(pa + 64 * NM);
        la3 = *(const f32x4*)(pa + 96 * NM);
        const float* p1 = w1g + (size_t)(k0 + w_kq * 4) * NH + w_cg * 4;
        l10 = *(const f32x4*)(p1);
        l11 = *(const f32x4*)(p1 + NH);
        l12 = *(const f32x4*)(p1 + 2 * NH);
        l13 = *(const f32x4*)(p1 + 3 * NH);
        const float* p3 = w3g + (size_t)(k0 + w_kq * 4) * NH + w_cg * 4;
        l30 = *(const f32x4*)(p3);
        l31 = *(const f32x4*)(p3 + NH);
        l32 = *(const f32x4*)(p3 + 2 * NH);
        l33 = *(const f32x4*)(p3 + 3 * NH);
    };

    auto stage_write = [&](int buf) {
        unsigned char* base = lds + buf * (3 * TILEB);
        unsigned char* pa = base + a_r * ROWB + a_c4 * 8;
        *(u16x4*)(pa)             = (u16x4){f2bf(la0[0]), f2bf(la0[1]), f2bf(la0[2]), f2bf(la0[3])};
        *(u16x4*)(pa + 32 * ROWB) = (u16x4){f2bf(la1[0]), f2bf(la1[1]), f2bf(la1[2]), f2bf(la1[3])};
        *(u16x4*)(pa + 64 * ROWB) = (u16x4){f2bf(la2[0]), f2bf(la2[1]), f2bf(la2[2]), f2bf(la2[3])};
        *(u16x4*)(pa + 96 * ROWB) = (u16x4){f2bf(la3[0]), f2bf(la3[1]), f2bf(la3[2]), f2bf(la3[3])};
        unsigned char* pw1 = base + TILEB + w_kq * 8;
#pragma unroll
        for (int j = 0; j < 4; ++j) {
            const int c = w_cg * 4 + j;
            *(u16x4*)(pw1 + c * ROWB) =
                (u16x4){f2bf(l10[j]), f2bf(l11[j]), f2bf(l12[j]), f2bf(l13[j])};
        }
        unsigned char* pw3 = base + 2 * TILEB + w_kq * 8;
#pragma unroll
        for (int j = 0; j < 4; ++j) {
            const int c = w_cg * 4 + j;
            *(u16x4*)(pw3 + c * ROWB) =
                (u16x4){f2bf(l30[j]), f2bf(l31[j]), f2bf(l32[j]), f2bf(l33[j])};
        }
    };

    auto compute = [&](int buf) {
        const unsigned char* base = lds + buf * (3 * TILEB);
        bf16x8 af[4], b1f[4], b3f[4];
#pragma unroll
        for (int m = 0; m < 4; ++m)
            af[m] = *(const bf16x8*)(base + (r0w + m * 16 + lr) * ROWB + lq * 16);
#pragma unroll
        for (int n = 0; n < 4; ++n) {
            b1f[n] = *(const bf16x8*)(base + TILEB + (c0w + n * 16 + lr) * ROWB + lq * 16);
            b3f[n] = *(const bf16x8*)(base + 2 * TILEB + (c0w + n * 16 + lr) * ROWB + lq * 16);
        }
#pragma unroll
        for (int m = 0; m < 4; ++m)
#pragma unroll
            for (int n = 0; n < 4; ++n) {
                accg[m][n] = __builtin_amdgcn_mfma_f32_16x16x32_bf16(af[m], b1f[n], accg[m][n], 0, 0, 0);
                accu[m][n] = __builtin_amdgcn_mfma_f32_16x16x32_bf16(af[m], b3f[n], accu[m][n], 0, 0, 0);
            }
    };

    stage_load(0);
    stage_write(0);
    __syncthreads();
    int cur = 0;
    const int NK = NM / 32;
    for (int ks = 0; ks < NK; ++ks) {
        const bool more = (ks + 1 < NK);
        if (more) stage_load(ks + 1);
        compute(cur);
        if (more) {
            stage_write(cur ^ 1);
            __syncthreads();
        }
        cur ^= 1;
    }

#pragma unroll
    for (int m = 0; m < 4; ++m)
#pragma unroll
        for (int n = 0; n < 4; ++n)
#pragma unroll
            for (int i = 0; i < 4; ++i) {
                const float g = accg[m][n][i];
                const float u = accu[m][n][i];
                const float s = g / (1.f + __expf(-g));
                const int r = r0w + m * 16 + lq * 4 + i;
                const int c = c0w + n * 16 + lr;
                hg[(size_t)r * NH + c] = f2bf(s * u);
            }
}

__global__ __launch_bounds__(256, 2) void gemm2_fb_kernel(
        const unsigned short* __restrict__ hid, const float* __restrict__ w2,
        float* __restrict__ out) {
    const int tid = threadIdx.x;
    const int e = blockIdx.y;
    const int d = blockIdx.x;
    const int l = (d & 7) * 32 + (d >> 3);
    const int mn = l >> 4, tm = l & 15;

    const unsigned short* ag = hid + (size_t)(e * NT + tm * 128) * NH;
    const float* wg = w2 + (size_t)e * NH * NM + mn * 128;
    float* og = out + (size_t)(e * NT + tm * 128) * NM + mn * 128;

    __shared__ __align__(16) unsigned char lds[2 * 2 * TILEB];

    const int a_row = tid >> 2, a_ch = tid & 3;
    const int w_kq = (tid >> 2) & 7;
    const int w_cg = ((tid >> 5) << 2) | (tid & 3);

    const int lane = tid & 63;
    const int wv = tid >> 6;
    const int r0w = (wv >> 1) * 64, c0w = (wv & 1) * 64;
    const int lr = lane & 15, lq = lane >> 4;

    f32x4 acc[4][4];
#pragma unroll
    for (int m = 0; m < 4; ++m)
#pragma unroll
        for (int n = 0; n < 4; ++n) acc[m][n] = (f32x4){0.f, 0.f, 0.f, 0.f};

    u32x4 lau0, lau1;
    f32x4 lw0, lw1, lw2, lw3;

    auto stage_load = [&](int ks) {
        const int k0 = ks * 32;
        lau0 = *(const u32x4*)(ag + (size_t)a_row * NH + k0 + a_ch * 8);
        lau1 = *(const u32x4*)(ag + (size_t)(a_row + 64) * NH + k0 + a_ch * 8);
        const float* p = wg + (size_t)(k0 + w_kq * 4) * NM + w_cg * 4;
        lw0 = *(const f32x4*)(p);
        lw1 = *(const f32x4*)(p + NM);
        lw2 = *(const f32x4*)(p + 2 * NM);
        lw3 = *(const f32x4*)(p + 3 * NM);
    };

    auto stage_write = [&](int buf) {
        unsigned char* base = lds + buf * (2 * TILEB);
        *(u32x4*)(base + a_row * ROWB + a_ch * 16) = lau0;
        *(u32x4*)(base + (a_row + 64) * ROWB + a_ch * 16) = lau1;
        unsigned char* pw = base + TILEB + w_kq * 8;
#pragma unroll
        for (int j = 0; j < 4; ++j) {
            const int c = w_cg * 4 + j;
            *(u16x4*)(pw + c * ROWB) =
                (u16x4){f2bf(lw0[j]), f2bf(lw1[j]), f2bf(lw2[j]), f2bf(lw3[j])};
        }
    };

    auto compute = [&](int buf) {
        const unsigned char* base = lds + buf * (2 * TILEB);
        bf16x8 af[4], bf[4];
#pragma unroll
        for (int m = 0; m < 4; ++m)
            af[m] = *(const bf16x8*)(base + (r0w + m * 16 + lr) * ROWB + lq * 16);
#pragma unroll
        for (int n = 0; n < 4; ++n)
            bf[n] = *(const bf16x8*)(base + TILEB + (c0w + n * 16 + lr) * ROWB + lq * 16);
#pragma unroll
        for (int m = 0; m < 4; ++m)
#pragma unroll
            for (int n = 0; n < 4; ++n)
                acc[m][n] = __builtin_amdgcn_mfma_f32_16x16x32_bf16(af[m], bf[n], acc[m][n], 0, 0, 0);
    };

    stage_load(0);
    stage_write(0);
    __syncthreads();
    int cur = 0;
    const int NK = NH / 32;
    for (int ks = 0; ks < NK; ++ks) {
        const bool more = (ks + 1 < NK);
        if (more) stage_load(ks + 1);
        compute(cur);
        if (more) {
            stage_write(cur ^ 1);
            __syncthreads();
        }
        cur ^= 1;
    }

#pragma unroll
    for (int m = 0; m < 4; ++m)
#pragma unroll
        for (int n = 0; n < 4; ++n)
#pragma unroll
            for (int i = 0; i < 4; ++i) {
                const int r = r0w + m * 16 + lq * 4 + i;
                const int c = c0w + n * 16 + lr;
                og[(size_t)r * NM + c] = acc[m][n][i];
            }
}

// ================================ launcher ================================

extern "C" void kernel_launch(void* const* d_in, const int* in_sizes, int n_in,
                              void* d_out, int out_size, void* d_ws, size_t ws_size,
                              hipStream_t stream) {
    const float* x  = (const float*)d_in[0];
    const float* w1 = (const float*)d_in[1];
    const float* w2 = (const float*)d_in[2];
    const float* w3 = (const float*)d_in[3];
    float* out = (float*)d_out;

    const size_t XB_SZ   = (size_t)NE * NT * NM * 2;        //  64 MiB
    const size_t WCAT_SZ = (size_t)NE * 2 * NH * NM * 2;    // 448 MiB
    const size_t HID_SZ  = (size_t)NE * NT * NH * 2;        // 224 MiB
    const size_t W2T_SZ  = (size_t)NE * NM * NH * 2;        // 224 MiB
    const size_t NEED_FULL = XB_SZ + WCAT_SZ + HID_SZ + W2T_SZ;  // 960 MiB
    const size_t NEED_STD  = XB_SZ + WCAT_SZ + HID_SZ;           // 736 MiB

    unsigned char* ws = (unsigned char*)d_ws;

    if (ws_size >= NEED_FULL) {
        unsigned short* xbp  = (unsigned short*)(ws);
        unsigned short* wcat = (unsigned short*)(ws + XB_SZ);
        unsigned short* hidb = (unsigned short*)(ws + XB_SZ + WCAT_SZ);
        unsigned short* w2t  = (unsigned short*)(ws + XB_SZ + WCAT_SZ + HID_SZ);

        convert_x_kernel<<<dim3((NE * NT * NM / 8) / 256), 256, 0, stream>>>(x, xbp);
        convert_w13_kernel<<<dim3((NM / 64) * (NH / 64), NE), 256, 0, stream>>>(w1, w3, wcat);
        gemm1p_kernel<<<dim3(448 + 1792, NE), 512, 0, stream>>>(xbp, wcat, hidb, w2, w2t);
        gemm2p_kernel<<<dim3(64, NE), 512, 0, stream>>>(hidb, w2t, out);
    } else if (ws_size >= NEED_STD) {
        unsigned short* xbp  = (unsigned short*)(ws);
        unsigned short* wcat = (unsigned short*)(ws + XB_SZ);
        unsigned short* hidb = (unsigned short*)(ws + XB_SZ + WCAT_SZ);
        unsigned short* w2t  = (unsigned short*)(ws);   // reuses xb/wcat after gemm1

        convert_x_kernel<<<dim3((NE * NT * NM / 8) / 256), 256, 0, stream>>>(x, xbp);
        convert_w13_kernel<<<dim3((NM / 64) * (NH / 64), NE), 256, 0, stream>>>(w1, w3, wcat);
        gemm1p_kernel<<<dim3(448, NE), 512, 0, stream>>>(xbp, wcat, hidb, w2, w2t);
        convert_w2t_kernel<<<dim3((NH / 64) * (NM / 64), NE), 256, 0, stream>>>(w2, w2t);
        gemm2p_kernel<<<dim3(64, NE), 512, 0, stream>>>(hidb, w2t, out);
    } else {
        unsigned short* hid = (unsigned short*)d_ws;
        gemm1_fb_kernel<<<dim3(896, NE), 256, 0, stream>>>(x, w1, w3, hid);
        gemm2_fb_kernel<<<dim3(256, NE), 256, 0, stream>>>(hid, w2, out);
    }
}